// Round 6
// baseline (3293.075 us; speedup 1.0000x reference)
//
#include <hip/hip_runtime.h>

typedef __bf16 bf16x8 __attribute__((ext_vector_type(8)));
typedef __bf16 bf16x4 __attribute__((ext_vector_type(4)));
typedef float f32x4 __attribute__((ext_vector_type(4)));
typedef unsigned short u16;
typedef unsigned short u16x8 __attribute__((ext_vector_type(8)));

#define DIM 4096
#define NHEADS 32
#define NKV 8
#define HD 128
#define BB 2
#define SS 2048
#define MROWS (BB*SS)        // 4096
#define QKVP 6144            // fused QKV row pitch (4096 Q | 1024 K | 1024 V)
#define QSCALE 0.08838834764831843f  // 1/sqrt(128)

#define WAIT_LGKM0 asm volatile("s_waitcnt lgkmcnt(0)" ::: "memory")
#define WAIT_VM0   asm volatile("s_waitcnt vmcnt(0)" ::: "memory")
#define SGB0       __builtin_amdgcn_sched_barrier(0)

__device__ __forceinline__ u16 f2bf(float f) {
  unsigned int u = __float_as_uint(f);
  u += 0x7fffu + ((u >> 16) & 1u);   // round-to-nearest-even
  return (u16)(u >> 16);
}

__device__ __forceinline__ void gload16(const void* g, void* l) {
  __builtin_amdgcn_global_load_lds(
      (const __attribute__((address_space(1))) unsigned int*)g,
      (__attribute__((address_space(3))) unsigned int*)l, 16, 0, 0);
}

__device__ __forceinline__ bf16x4 tr16(const void* p) {
  bf16x4 d;
  asm volatile("ds_read_b64_tr_b16 %0, %1"
               : "=v"(d)
               : "v"((const __attribute__((address_space(3))) u16*)p)
               : "memory");
  return d;
}

template<int CTRL>
__device__ __forceinline__ float dpp_ror(float x) {
  return __int_as_float(__builtin_amdgcn_update_dpp(
      0, __float_as_int(x), CTRL, 0xF, 0xF, false));
}
__device__ __forceinline__ float red16_max(float v) {
  v = fmaxf(v, dpp_ror<0x121>(v));
  v = fmaxf(v, dpp_ror<0x122>(v));
  v = fmaxf(v, dpp_ror<0x124>(v));
  v = fmaxf(v, dpp_ror<0x128>(v));
  return v;
}
__device__ __forceinline__ float red16_sum(float v) {
  v += dpp_ror<0x121>(v);
  v += dpp_ror<0x122>(v);
  v += dpp_ror<0x124>(v);
  v += dpp_ror<0x128>(v);
  return v;
}

// ---------------- fp32 -> bf16 conversion, all 4 tensors in one launch ----------------
__global__ __launch_bounds__(256) void f2b4_kernel(
    const float* __restrict__ xa, const float* __restrict__ xb,
    const float* __restrict__ xc, const float* __restrict__ xd,
    u16* __restrict__ oa, u16* __restrict__ ob,
    u16* __restrict__ oc, u16* __restrict__ od) {
  int i = blockIdx.x * 256 + threadIdx.x;
  const float* in; u16* out; int k;
  if (i < 2097152)      { in = xa; out = oa; k = i; }
  else if (i < 4194304) { in = xb; out = ob; k = i - 2097152; }
  else if (i < 5242880) { in = xc; out = oc; k = i - 4194304; }
  else                  { in = xd; out = od; k = i - 5242880; }
  const float4* in4 = (const float4*)in;
  float4 a = in4[2*(size_t)k];
  float4 b = in4[2*(size_t)k + 1];
  u16x8 o;
  o[0]=f2bf(a.x); o[1]=f2bf(a.y); o[2]=f2bf(a.z); o[3]=f2bf(a.w);
  o[4]=f2bf(b.x); o[5]=f2bf(b.y); o[6]=f2bf(b.z); o[7]=f2bf(b.w);
  ((u16x8*)out)[k] = o;
}

// ---------------- 256x128 / BK=32 / 8-wave GEMM, C = A @ B^T ----------------
// 2-deep dbuf, 48 KiB LDS -> 3 blocks/CU (cross-block TLP covers drain stalls,
// m97/m114 mechanism). One barrier per K-tile: {8 ds_read, 3 gload_lds,
// lgkm0, 16 MFMA, vm0, barrier}. All addresses hoisted; 64B ptr increments.
// LDS per buf: A 16KB (128 ldsrows) @0, B 8KB (64 ldsrows) @16384; ldsrow j
// holds tile rows {2j,2j+1}; stored 16B-chunk c = src chunk ^ (j&7) (rule 21).
template<int OUTF32>
__global__ __launch_bounds__(512, 6) void gemm256(
    const u16* __restrict__ A, const u16* __restrict__ Bm, void* __restrict__ C,
    int M, int N, int K, int nbx, int acut, float a0, float a1) {
  __shared__ char smem[49152];            // buf b at b*24576

  const int t = threadIdx.x;
  const int l = t & 63, w = t >> 6;
  const int l15 = l & 15, l4 = l >> 4;
  const int wm = w >> 1, wn = w & 1;      // 4 x 2 wave grid, 64x64 per wave

  // bijective XCD swizzle (nwg % 8 == 0 for all our grids)
  const int nwg = gridDim.x;
  const int cpx = nwg >> 3;
  const int sw = (blockIdx.x & 7) * cpx + (blockIdx.x >> 3);
  const int bx = sw % nbx, by = sw / nbx;
  const int row0 = by * 256, col0 = bx * 128;
  const float alpha = (col0 < acut) ? a0 : a1;

  f32x4 acc[4][4] = {};

  // ---- hoisted stage addressing (wave w: A chunks {w, w+8}, B chunk w) ----
  const int u = w*64 + l;                 // 16B unit within 1KB-chunk group
  const int j0 = u >> 3;
  const int cs = (u & 7) ^ (j0 & 7);      // inverse-swizzled source chunk
  const int r0 = 2*j0 + (cs >> 2);
  const int kc = (cs & 3) * 8;
  const char* gA0 = (const char*)(A  + (size_t)(row0 + r0)       * K + kc);
  const char* gA1 = (const char*)(A  + (size_t)(row0 + r0 + 128) * K + kc);
  const char* gB0 = (const char*)(Bm + (size_t)(col0 + r0)       * K + kc);
  const int wA0 = w*1024, wA1 = w*1024 + 8192, wB0 = 16384 + w*1024;

  auto stage = [&](int lbase) {
    gload16(gA0, (char*)smem + lbase + wA0);
    gload16(gA1, (char*)smem + lbase + wA1);
    gload16(gB0, (char*)smem + lbase + wB0);
    gA0 += 64; gA1 += 64; gB0 += 64;      // 32 bf16 per K-tile
  };

  // ---- hoisted LDS read offsets ----
  int offA0, offA1, offA2, offA3, offB0, offB1, offB2, offB3;
  {
    int r, j, c;
    r = wm*64 +  0 + l15; j = r>>1; c = ((r&1)*4 + l4) ^ (j&7); offA0 = j*128 + c*16;
    r = wm*64 + 16 + l15; j = r>>1; c = ((r&1)*4 + l4) ^ (j&7); offA1 = j*128 + c*16;
    r = wm*64 + 32 + l15; j = r>>1; c = ((r&1)*4 + l4) ^ (j&7); offA2 = j*128 + c*16;
    r = wm*64 + 48 + l15; j = r>>1; c = ((r&1)*4 + l4) ^ (j&7); offA3 = j*128 + c*16;
    r = wn*64 +  0 + l15; j = r>>1; c = ((r&1)*4 + l4) ^ (j&7); offB0 = 16384 + j*128 + c*16;
    r = wn*64 + 16 + l15; j = r>>1; c = ((r&1)*4 + l4) ^ (j&7); offB1 = 16384 + j*128 + c*16;
    r = wn*64 + 32 + l15; j = r>>1; c = ((r&1)*4 + l4) ^ (j&7); offB2 = 16384 + j*128 + c*16;
    r = wn*64 + 48 + l15; j = r>>1; c = ((r&1)*4 + l4) ^ (j&7); offB3 = 16384 + j*128 + c*16;
  }

  const int nt = K >> 5;                  // K-tiles of 32 (even)
  stage(0);
  WAIT_VM0;
  __builtin_amdgcn_s_barrier();

  auto body = [&](int rb, int sb, bool dostage) {
    const char* Sb = (const char*)smem + rb;
    bf16x8 a0 = *(const bf16x8*)(Sb + offA0);
    bf16x8 a1 = *(const bf16x8*)(Sb + offA1);
    bf16x8 a2 = *(const bf16x8*)(Sb + offA2);
    bf16x8 a3 = *(const bf16x8*)(Sb + offA3);
    bf16x8 b0 = *(const bf16x8*)(Sb + offB0);
    bf16x8 b1 = *(const bf16x8*)(Sb + offB1);
    bf16x8 b2 = *(const bf16x8*)(Sb + offB2);
    bf16x8 b3 = *(const bf16x8*)(Sb + offB3);
    if (dostage) stage(sb);
    WAIT_LGKM0; SGB0;
    __builtin_amdgcn_s_setprio(1);
    acc[0][0] = __builtin_amdgcn_mfma_f32_16x16x32_bf16(a0, b0, acc[0][0], 0, 0, 0);
    acc[0][1] = __builtin_amdgcn_mfma_f32_16x16x32_bf16(a0, b1, acc[0][1], 0, 0, 0);
    acc[0][2] = __builtin_amdgcn_mfma_f32_16x16x32_bf16(a0, b2, acc[0][2], 0, 0, 0);
    acc[0][3] = __builtin_amdgcn_mfma_f32_16x16x32_bf16(a0, b3, acc[0][3], 0, 0, 0);
    acc[1][0] = __builtin_amdgcn_mfma_f32_16x16x32_bf16(a1, b0, acc[1][0], 0, 0, 0);
    acc[1][1] = __builtin_amdgcn_mfma_f32_16x16x32_bf16(a1, b1, acc[1][1], 0, 0, 0);
    acc[1][2] = __builtin_amdgcn_mfma_f32_16x16x32_bf16(a1, b2, acc[1][2], 0, 0, 0);
    acc[1][3] = __builtin_amdgcn_mfma_f32_16x16x32_bf16(a1, b3, acc[1][3], 0, 0, 0);
    acc[2][0] = __builtin_amdgcn_mfma_f32_16x16x32_bf16(a2, b0, acc[2][0], 0, 0, 0);
    acc[2][1] = __builtin_amdgcn_mfma_f32_16x16x32_bf16(a2, b1, acc[2][1], 0, 0, 0);
    acc[2][2] = __builtin_amdgcn_mfma_f32_16x16x32_bf16(a2, b2, acc[2][2], 0, 0, 0);
    acc[2][3] = __builtin_amdgcn_mfma_f32_16x16x32_bf16(a2, b3, acc[2][3], 0, 0, 0);
    acc[3][0] = __builtin_amdgcn_mfma_f32_16x16x32_bf16(a3, b0, acc[3][0], 0, 0, 0);
    acc[3][1] = __builtin_amdgcn_mfma_f32_16x16x32_bf16(a3, b1, acc[3][1], 0, 0, 0);
    acc[3][2] = __builtin_amdgcn_mfma_f32_16x16x32_bf16(a3, b2, acc[3][2], 0, 0, 0);
    acc[3][3] = __builtin_amdgcn_mfma_f32_16x16x32_bf16(a3, b3, acc[3][3], 0, 0, 0);
    __builtin_amdgcn_s_setprio(0);
    WAIT_VM0;                             // next buffer landed (own 3 loads)
    __builtin_amdgcn_s_barrier();         // all waves: reads retired + stages landed
  };

  for (int kt = 0; kt < nt; kt += 2) {
    body(0,     24576, kt + 1 < nt);
    body(24576, 0,     kt + 2 < nt);
  }

  // epilogue: C/D layout col=lane&15, row=(lane>>4)*4+reg
  #pragma unroll
  for (int mi = 0; mi < 4; ++mi) {
    #pragma unroll
    for (int ni = 0; ni < 4; ++ni) {
      #pragma unroll
      for (int r = 0; r < 4; ++r) {
        size_t rr = (size_t)(row0 + wm*64 + mi*16 + l4*4 + r);
        size_t cc = (size_t)(col0 + wn*64 + ni*16 + l15);
        float v = acc[mi][ni][r] * alpha;
        if (OUTF32) ((float*)C)[rr*(size_t)N + cc] = v;
        else        ((u16*)C)[rr*(size_t)N + cc] = f2bf(v);
      }
    }
  }
}

// ---------------- causal GQA flash attention (QKVP pitch) ----------------
__global__ __launch_bounds__(256, 2) void attn_kernel(
    const u16* __restrict__ QKV,  // [4096][6144]: 0..4095 Q | 4096..5119 K | 5120..6143 V
    u16* __restrict__ O) {        // [4096][4096]
  __shared__ u16 Ks[2][64*128];
  __shared__ u16 Vs[2][64*128];
  __shared__ u16 Ps[4][1024];
  const int t = threadIdx.x;
  const int l = t & 63, w = t >> 6;
  const int l15 = l & 15, l4 = l >> 4;
  const int pair = blockIdx.x, h = blockIdx.y, b = blockIdx.z;
  const int hkv = h >> 2;
  const u16* Kg = QKV + (size_t)(b*SS) * QKVP + DIM + hkv*HD;
  const u16* Vg = Kg + NKV*HD;
  u16* Pw = &Ps[w][0];

  auto stage = [&](u16* Ksb, u16* Vsb, int kv0) {
    const u16* Kr = Kg + (size_t)kv0 * QKVP;
    const u16* Vr = Vg + (size_t)kv0 * QKVP;
    #pragma unroll
    for (int i = 0; i < 4; ++i) {
      int o = i*4096 + w*1024 + l*16;
      int row = o >> 8;
      int sc = l15 ^ (row & 7);
      gload16((const char*)(Kr + (size_t)row * QKVP) + sc*16,
              (char*)Ksb + i*4096 + w*1024);
    }
    #pragma unroll
    for (int i = 0; i < 4; ++i) {
      int cb = i*4 + w;
      int kv = cb*4 + ((l & 7) >> 1);
      int d0 = ((l >> 3) << 4) + (l & 1)*8;
      gload16((const char*)(Vr + (size_t)kv * QKVP + d0),
              (char*)Vsb + cb*1024);
    }
  };

  for (int half = 0; half < 2; ++half) {
    const int qb = half ? (15 - pair) : pair;
    const int q0 = qb * 128;
    const int q0w = q0 + w*32;

    const size_t qbase = ((size_t)(b*SS + q0w)) * QKVP + h*HD;
    bf16x8 qf[2][4];
    #pragma unroll
    for (int m = 0; m < 2; ++m)
      #pragma unroll
      for (int kd = 0; kd < 4; ++kd)
        qf[m][kd] = *(const bf16x8*)&QKV[qbase + (size_t)(m*16 + l15)*QKVP + kd*32 + l4*8];

    f32x4 oacc[2][8] = {};
    float mrun[2][4], lrun[2][4];
    #pragma unroll
    for (int m = 0; m < 2; ++m)
      #pragma unroll
      for (int r = 0; r < 4; ++r) { mrun[m][r] = -1e30f; lrun[m][r] = 0.f; }

    const int nst = 2*qb + 2;
    stage(Ks[0], Vs[0], 0);
    WAIT_VM0;
    __builtin_amdgcn_s_barrier();
    SGB0;

    for (int st = 0; st < nst; ++st) {
      const int kv0 = st * 64;
      u16* Ksb = Ks[st & 1];
      u16* Vsb = Vs[st & 1];
      if (st + 1 < nst) stage(Ks[(st+1) & 1], Vs[(st+1) & 1], kv0 + 64);

      if (kv0 <= q0w + 31) {
        f32x4 sacc[2][4] = {};
        __builtin_amdgcn_s_setprio(1);
        #pragma unroll
        for (int kd = 0; kd < 4; ++kd) {
          bf16x8 kf[4];
          #pragma unroll
          for (int n = 0; n < 4; ++n) {
            int row = n*16 + l15;
            int off = (row << 8) | (((kd*4 + l4) ^ (row & 7)) << 4);
            kf[n] = *(const bf16x8*)((const char*)Ksb + off);
          }
          #pragma unroll
          for (int m = 0; m < 2; ++m)
            #pragma unroll
            for (int n = 0; n < 4; ++n)
              sacc[m][n] = __builtin_amdgcn_mfma_f32_16x16x32_bf16(qf[m][kd], kf[n], sacc[m][n], 0, 0, 0);
        }
        __builtin_amdgcn_s_setprio(0);

        if (st >= 2*qb) {
          #pragma unroll
          for (int n = 0; n < 4; ++n) {
            int ki = kv0 + n*16 + l15;
            #pragma unroll
            for (int m = 0; m < 2; ++m)
              #pragma unroll
              for (int r = 0; r < 4; ++r) {
                int qi = q0w + m*16 + l4*4 + r;
                if (ki > qi) sacc[m][n][r] = -1e30f;
              }
          }
        }

        float pr[2][4][4];
        #pragma unroll
        for (int m = 0; m < 2; ++m) {
          #pragma unroll
          for (int r = 0; r < 4; ++r) {
            float s0 = sacc[m][0][r], s1 = sacc[m][1][r];
            float s2 = sacc[m][2][r], s3 = sacc[m][3][r];
            float vm = fmaxf(fmaxf(s0, s1), fmaxf(s2, s3));
            vm = red16_max(vm);
            float mo = mrun[m][r];
            float mnew = fmaxf(mo, vm);
            float al = __expf(mo - mnew);
            float p0 = __expf(s0 - mnew), p1 = __expf(s1 - mnew);
            float p2 = __expf(s2 - mnew), p3 = __expf(s3 - mnew);
            float rs = red16_sum((p0 + p1) + (p2 + p3));
            mrun[m][r] = mnew;
            lrun[m][r] = lrun[m][r]*al + rs;
            #pragma unroll
            for (int dn = 0; dn < 8; ++dn) oacc[m][dn][r] *= al;
            pr[m][r][0] = p0; pr[m][r][1] = p1; pr[m][r][2] = p2; pr[m][r][3] = p3;
          }
        }

        #pragma unroll
        for (int kvh = 0; kvh < 2; ++kvh) {
          #pragma unroll
          for (int m = 0; m < 2; ++m)
            #pragma unroll
            for (int nn = 0; nn < 2; ++nn) {
              int n = kvh*2 + nn;
              bf16x4 w4;
              w4[0] = (__bf16)pr[m][0][n]; w4[1] = (__bf16)pr[m][1][n];
              w4[2] = (__bf16)pr[m][2][n]; w4[3] = (__bf16)pr[m][3][n];
              *(bf16x4*)((char*)Pw + ((nn*4 + (l15 >> 2))*2 + m)*128
                                   + (l15 & 3)*32 + l4*8) = w4;
            }
          const char* pb = (const char*)Pw + l4*512 + l15*8;
          bf16x4 a00 = tr16(pb);
          bf16x4 a01 = tr16(pb + 256);
          bf16x4 a10 = tr16(pb + 128);
          bf16x4 a11 = tr16(pb + 384);
          const char* vb = (const char*)Vsb + l4*2048 + l15*8 + kvh*8192;
          bf16x4 b0[8], b1[8];
          #pragma unroll
          for (int dn = 0; dn < 8; ++dn) {
            b0[dn] = tr16(vb + dn*128);
            b1[dn] = tr16(vb + dn*128 + 1024);
          }
          WAIT_LGKM0; SGB0;
          bf16x8 pa0 = __builtin_shufflevector(a00, a01, 0,1,2,3,4,5,6,7);
          bf16x8 pa1 = __builtin_shufflevector(a10, a11, 0,1,2,3,4,5,6,7);
          __builtin_amdgcn_s_setprio(1);
          #pragma unroll
          for (int dn = 0; dn < 8; ++dn) {
            bf16x8 v8 = __builtin_shufflevector(b0[dn], b1[dn], 0,1,2,3,4,5,6,7);
            oacc[0][dn] = __builtin_amdgcn_mfma_f32_16x16x32_bf16(pa0, v8, oacc[0][dn], 0, 0, 0);
            oacc[1][dn] = __builtin_amdgcn_mfma_f32_16x16x32_bf16(pa1, v8, oacc[1][dn], 0, 0, 0);
          }
          __builtin_amdgcn_s_setprio(0);
        }
      }

      WAIT_VM0;
      __builtin_amdgcn_s_barrier();
      SGB0;
    }

    const size_t obase = ((size_t)(b*SS + q0w)) * DIM + h*HD;
    #pragma unroll
    for (int m = 0; m < 2; ++m) {
      #pragma unroll
      for (int r = 0; r < 4; ++r) {
        float inv = 1.0f / lrun[m][r];
        int srow = m*16 + l4*4 + r;
        #pragma unroll
        for (int dn = 0; dn < 8; ++dn)
          O[obase + (size_t)srow*DIM + dn*16 + l15] = f2bf(oacc[m][dn][r] * inv);
      }
    }
  }
}

extern "C" void kernel_launch(void* const* d_in, const int* in_sizes, int n_in,
                              void* d_out, int out_size, void* d_ws, size_t ws_size,
                              hipStream_t stream) {
  const float* x   = (const float*)d_in[0];
  const float* Wq  = (const float*)d_in[1];
  const float* Wkv = (const float*)d_in[2];
  const float* Wo  = (const float*)d_in[3];

  if (ws_size < (160ull << 20)) return;
  char* ws = (char*)d_ws;
  u16* xb   = (u16*)(ws);                  // 32 MB [4096][4096]
  u16* Wqb  = (u16*)(ws + (32ull  << 20)); // 32 MB [4096][4096]  \ fused W rows 0..6143
  u16* Wkvb = (u16*)(ws + (64ull  << 20)); // 16 MB [2048][4096]  /
  u16* Wob  = (u16*)(ws + (80ull  << 20)); // 32 MB [4096][4096]
  u16* QKVb = (u16*)(ws + (112ull << 20)); // 48 MB [4096][6144]
  u16* attnb = xb;                         // alias after projections

  // fp32 -> bf16, one launch (x | Wq | Wkv | Wo)
  f2b4_kernel<<<28672, 256, 0, stream>>>(x, Wq, Wkv, Wo, xb, Wqb, Wkvb, Wob);

  // fused QKV projection: [4096][6144] = xb @ [Wq;Wkv]^T ; QSCALE on Q cols only
  // grid 768 = 3 x 256 CUs (3 blocks/CU co-resident)
  gemm256<0><<<dim3(16*48), 512, 0, stream>>>(xb, Wqb, QKVb,
                                              MROWS, QKVP, DIM, 48, DIM, QSCALE, 1.0f);

  attn_kernel<<<dim3(8, NHEADS, BB), 256, 0, stream>>>(QKVb, attnb);

  // output projection (fp32 out), grid 512 = 2 x 256 CUs
  gemm256<1><<<dim3(16*32), 512, 0, stream>>>(attnb, Wob, d_out,
                                              MROWS, DIM, DIM, 32, 0, 1.0f, 1.0f);
}

// Round 7
// 660.192 us; speedup vs baseline: 4.9881x; 4.9881x over previous
//
#include <hip/hip_runtime.h>

typedef __bf16 bf16x8 __attribute__((ext_vector_type(8)));
typedef __bf16 bf16x4 __attribute__((ext_vector_type(4)));
typedef float f32x4 __attribute__((ext_vector_type(4)));
typedef float f32x16 __attribute__((ext_vector_type(16)));
typedef unsigned short u16;
typedef unsigned short u16x8 __attribute__((ext_vector_type(8)));

#define DIM 4096
#define NHEADS 32
#define NKV 8
#define HD 128
#define BB 2
#define SS 2048
#define MROWS (BB*SS)        // 4096
#define QKVP 6144            // fused QKV row pitch (4096 Q | 1024 K | 1024 V)
#define QSCALE 0.08838834764831843f  // 1/sqrt(128)

#define WAIT_LGKM0 asm volatile("s_waitcnt lgkmcnt(0)" ::: "memory")
#define WAIT_VM0   asm volatile("s_waitcnt vmcnt(0)" ::: "memory")
#define WAIT_VM4   asm volatile("s_waitcnt vmcnt(4)" ::: "memory")
#define SGB0       __builtin_amdgcn_sched_barrier(0)

__device__ __forceinline__ u16 f2bf(float f) {
  unsigned int u = __float_as_uint(f);
  u += 0x7fffu + ((u >> 16) & 1u);   // round-to-nearest-even
  return (u16)(u >> 16);
}

__device__ __forceinline__ void gload16(const void* g, void* l) {
  __builtin_amdgcn_global_load_lds(
      (const __attribute__((address_space(1))) unsigned int*)g,
      (__attribute__((address_space(3))) unsigned int*)l, 16, 0, 0);
}

__device__ __forceinline__ bf16x4 tr16(const void* p) {
  bf16x4 d;
  asm volatile("ds_read_b64_tr_b16 %0, %1"
               : "=v"(d)
               : "v"((const __attribute__((address_space(3))) u16*)p)
               : "memory");
  return d;
}

template<int CTRL>
__device__ __forceinline__ float dpp_ror(float x) {
  return __int_as_float(__builtin_amdgcn_update_dpp(
      0, __float_as_int(x), CTRL, 0xF, 0xF, false));
}
__device__ __forceinline__ float red16_max(float v) {
  v = fmaxf(v, dpp_ror<0x121>(v));
  v = fmaxf(v, dpp_ror<0x122>(v));
  v = fmaxf(v, dpp_ror<0x124>(v));
  v = fmaxf(v, dpp_ror<0x128>(v));
  return v;
}
__device__ __forceinline__ float red16_sum(float v) {
  v += dpp_ror<0x121>(v);
  v += dpp_ror<0x122>(v);
  v += dpp_ror<0x124>(v);
  v += dpp_ror<0x128>(v);
  return v;
}

// ---------------- fp32 -> bf16 conversion, all 4 tensors in one launch ----------------
__global__ __launch_bounds__(256) void f2b4_kernel(
    const float* __restrict__ xa, const float* __restrict__ xb,
    const float* __restrict__ xc, const float* __restrict__ xd,
    u16* __restrict__ oa, u16* __restrict__ ob,
    u16* __restrict__ oc, u16* __restrict__ od) {
  int i = blockIdx.x * 256 + threadIdx.x;
  const float* in; u16* out; int k;
  if (i < 2097152)      { in = xa; out = oa; k = i; }
  else if (i < 4194304) { in = xb; out = ob; k = i - 2097152; }
  else if (i < 5242880) { in = xc; out = oc; k = i - 4194304; }
  else                  { in = xd; out = od; k = i - 5242880; }
  const float4* in4 = (const float4*)in;
  float4 a = in4[2*(size_t)k];
  float4 b = in4[2*(size_t)k + 1];
  u16x8 o;
  o[0]=f2bf(a.x); o[1]=f2bf(a.y); o[2]=f2bf(a.z); o[3]=f2bf(a.w);
  o[4]=f2bf(b.x); o[5]=f2bf(b.y); o[6]=f2bf(b.z); o[7]=f2bf(b.w);
  ((u16x8*)out)[k] = o;
}

// ---------------- 128x128 / BK=32 / 4-wave GEMM, 32x32x16 MFMA, C = A @ B^T ----------------
// 3 blocks/CU co-resident (reg-feasible: acc 64 AGPR + ~70 VGPR < 512/3):
// cross-block TLP covers staging latency (m97/m114 mechanism). 3-deep LDS
// ring (3 x 16KB), counted vmcnt(4) checkpoints - never drains mid-loop (T4).
// One barrier per K-tile. LDS per buf: A 8KB @0, B 8KB @8192; ldsrow j (128B)
// holds tile rows {2j,2j+1}; stored 16B-chunk c = src chunk ^ (j&7) (rule 21).
// Wave w (2x2 grid) owns 64x64 via 2x2 x mfma_32x32x16 (acc f32x16 each).
template<int OUTF32>
__global__ __launch_bounds__(256, 3) void gemm128(
    const u16* __restrict__ A, const u16* __restrict__ Bm, void* __restrict__ C,
    int M, int N, int K, int nbx, int acut, float a0, float a1) {
  __shared__ char smem[49152];            // buf b at b*16384

  const int t = threadIdx.x;
  const int l = t & 63, w = t >> 6;
  const int l31 = l & 31, lh = l >> 5;
  const int wm = w >> 1, wn = w & 1;      // 2 x 2 wave grid, 64x64 per wave

  // bijective XCD swizzle (nwg % 8 == 0 for all our grids)
  const int nwg = gridDim.x;
  const int cpx = nwg >> 3;
  const int sw = (blockIdx.x & 7) * cpx + (blockIdx.x >> 3);
  const int bx = sw % nbx, by = sw / nbx;
  const int row0 = by * 128, col0 = bx * 128;
  const float alpha = (col0 < acut) ? a0 : a1;

  f32x16 acc[2][2] = {};                  // [mf][nf], each 32x32

  // ---- stage addressing: 512 16B-units/matrix; thread t covers units t, t+256
  int ro0, ko0, ro1, ko1;
  {
    int o = t, j = o >> 3, cs = (o & 7) ^ (j & 7);
    ro0 = 2*j + (cs >> 2); ko0 = (cs & 3) * 8;
    o = t + 256; j = o >> 3; cs = (o & 7) ^ (j & 7);
    ro1 = 2*j + (cs >> 2); ko1 = (cs & 3) * 8;
  }
  const char* gA0 = (const char*)(A  + (size_t)(row0 + ro0) * K + ko0);
  const char* gA1 = (const char*)(A  + (size_t)(row0 + ro1) * K + ko1);
  const char* gB0 = (const char*)(Bm + (size_t)(col0 + ro0) * K + ko0);
  const char* gB1 = (const char*)(Bm + (size_t)(col0 + ro1) * K + ko1);

  auto stage = [&](int bsel) {
    char* d = (char*)smem + bsel * 16384;
    gload16(gA0, d + t*16);
    gload16(gA1, d + 4096 + t*16);
    gload16(gB0, d + 8192 + t*16);
    gload16(gB1, d + 12288 + t*16);
    gA0 += 64; gA1 += 64; gB0 += 64; gB1 += 64;   // 32 bf16 per K-tile
  };

  // ---- ds read base addrs (mf/nf=0; +2048 per 32-row frag step) ----
  // A-frag (32x32x16): row = base + (l&31), k = s*16 + (l>>5)*8 + j
  int adsA[2], adsB[2];
  #pragma unroll
  for (int s = 0; s < 2; ++s) {
    int r = wm*64 + l31;
    int j = r >> 1;
    int c = ((r & 1)*4 + s*2 + lh) ^ (j & 7);
    adsA[s] = j*128 + c*16;
    r = wn*64 + l31;
    j = r >> 1;
    c = ((r & 1)*4 + s*2 + lh) ^ (j & 7);
    adsB[s] = 8192 + j*128 + c*16;
  }

  const int nt = K >> 5;                  // K-tiles of 32
  stage(0); stage(1);
  WAIT_VM4;                               // buf0 landed (own loads)
  __builtin_amdgcn_s_barrier();           // everyone's buf0 landed

  int bsel = 0;
  for (int kt = 0; kt < nt; ++kt) {
    if (kt + 2 < nt) stage(bsel == 0 ? 2 : bsel - 1);   // (kt+2)%3
    const char* Sb = (const char*)smem + bsel * 16384;
    bf16x8 a00 = *(const bf16x8*)(Sb + adsA[0]);         // mf0 s0
    bf16x8 a01 = *(const bf16x8*)(Sb + adsA[1]);         // mf0 s1
    bf16x8 a10 = *(const bf16x8*)(Sb + adsA[0] + 2048);  // mf1 s0
    bf16x8 a11 = *(const bf16x8*)(Sb + adsA[1] + 2048);
    bf16x8 b00 = *(const bf16x8*)(Sb + adsB[0]);
    bf16x8 b01 = *(const bf16x8*)(Sb + adsB[1]);
    bf16x8 b10 = *(const bf16x8*)(Sb + adsB[0] + 2048);
    bf16x8 b11 = *(const bf16x8*)(Sb + adsB[1] + 2048);
    WAIT_LGKM0; SGB0;
    __builtin_amdgcn_s_setprio(1);
    acc[0][0] = __builtin_amdgcn_mfma_f32_32x32x16_bf16(a00, b00, acc[0][0], 0, 0, 0);
    acc[0][0] = __builtin_amdgcn_mfma_f32_32x32x16_bf16(a01, b01, acc[0][0], 0, 0, 0);
    acc[0][1] = __builtin_amdgcn_mfma_f32_32x32x16_bf16(a00, b10, acc[0][1], 0, 0, 0);
    acc[0][1] = __builtin_amdgcn_mfma_f32_32x32x16_bf16(a01, b11, acc[0][1], 0, 0, 0);
    acc[1][0] = __builtin_amdgcn_mfma_f32_32x32x16_bf16(a10, b00, acc[1][0], 0, 0, 0);
    acc[1][0] = __builtin_amdgcn_mfma_f32_32x32x16_bf16(a11, b01, acc[1][0], 0, 0, 0);
    acc[1][1] = __builtin_amdgcn_mfma_f32_32x32x16_bf16(a10, b10, acc[1][1], 0, 0, 0);
    acc[1][1] = __builtin_amdgcn_mfma_f32_32x32x16_bf16(a11, b11, acc[1][1], 0, 0, 0);
    __builtin_amdgcn_s_setprio(0);
    // counted checkpoint: next buf landed; 1 stage-set may stay in flight
    if (kt + 2 < nt)      { WAIT_VM4; }
    else if (kt + 1 < nt) { WAIT_VM0; }
    __builtin_amdgcn_s_barrier();         // reads retired before buf reuse (2 barriers ahead)
    bsel = (bsel == 2) ? 0 : bsel + 1;
  }

  // epilogue: 32x32 C/D layout col=lane&31, row=(reg&3)+8*(reg>>2)+4*(lane>>5)
  #pragma unroll
  for (int mf = 0; mf < 2; ++mf) {
    #pragma unroll
    for (int nf = 0; nf < 2; ++nf) {
      #pragma unroll
      for (int r = 0; r < 16; ++r) {
        size_t rr = (size_t)(row0 + wm*64 + mf*32 + (r & 3) + 8*(r >> 2) + 4*lh);
        size_t cc = (size_t)(col0 + wn*64 + nf*32 + l31);
        float v = acc[mf][nf][r] * alpha;
        if (OUTF32) ((float*)C)[rr*(size_t)N + cc] = v;
        else        ((u16*)C)[rr*(size_t)N + cc] = f2bf(v);
      }
    }
  }
}

// ---------------- causal GQA flash attention (QKVP pitch) ----------------
__global__ __launch_bounds__(256, 2) void attn_kernel(
    const u16* __restrict__ QKV,  // [4096][6144]: 0..4095 Q | 4096..5119 K | 5120..6143 V
    u16* __restrict__ O) {        // [4096][4096]
  __shared__ u16 Ks[2][64*128];
  __shared__ u16 Vs[2][64*128];
  __shared__ u16 Ps[4][1024];
  const int t = threadIdx.x;
  const int l = t & 63, w = t >> 6;
  const int l15 = l & 15, l4 = l >> 4;
  const int pair = blockIdx.x, h = blockIdx.y, b = blockIdx.z;
  const int hkv = h >> 2;
  const u16* Kg = QKV + (size_t)(b*SS) * QKVP + DIM + hkv*HD;
  const u16* Vg = Kg + NKV*HD;
  u16* Pw = &Ps[w][0];

  auto stage = [&](u16* Ksb, u16* Vsb, int kv0) {
    const u16* Kr = Kg + (size_t)kv0 * QKVP;
    const u16* Vr = Vg + (size_t)kv0 * QKVP;
    #pragma unroll
    for (int i = 0; i < 4; ++i) {
      int o = i*4096 + w*1024 + l*16;
      int row = o >> 8;
      int sc = l15 ^ (row & 7);
      gload16((const char*)(Kr + (size_t)row * QKVP) + sc*16,
              (char*)Ksb + i*4096 + w*1024);
    }
    #pragma unroll
    for (int i = 0; i < 4; ++i) {
      int cb = i*4 + w;
      int kv = cb*4 + ((l & 7) >> 1);
      int d0 = ((l >> 3) << 4) + (l & 1)*8;
      gload16((const char*)(Vr + (size_t)kv * QKVP + d0),
              (char*)Vsb + cb*1024);
    }
  };

  for (int half = 0; half < 2; ++half) {
    const int qb = half ? (15 - pair) : pair;
    const int q0 = qb * 128;
    const int q0w = q0 + w*32;

    const size_t qbase = ((size_t)(b*SS + q0w)) * QKVP + h*HD;
    bf16x8 qf[2][4];
    #pragma unroll
    for (int m = 0; m < 2; ++m)
      #pragma unroll
      for (int kd = 0; kd < 4; ++kd)
        qf[m][kd] = *(const bf16x8*)&QKV[qbase + (size_t)(m*16 + l15)*QKVP + kd*32 + l4*8];

    f32x4 oacc[2][8] = {};
    float mrun[2][4], lrun[2][4];
    #pragma unroll
    for (int m = 0; m < 2; ++m)
      #pragma unroll
      for (int r = 0; r < 4; ++r) { mrun[m][r] = -1e30f; lrun[m][r] = 0.f; }

    const int nst = 2*qb + 2;
    stage(Ks[0], Vs[0], 0);
    WAIT_VM0;
    __builtin_amdgcn_s_barrier();
    SGB0;

    for (int st = 0; st < nst; ++st) {
      const int kv0 = st * 64;
      u16* Ksb = Ks[st & 1];
      u16* Vsb = Vs[st & 1];
      if (st + 1 < nst) stage(Ks[(st+1) & 1], Vs[(st+1) & 1], kv0 + 64);

      if (kv0 <= q0w + 31) {
        f32x4 sacc[2][4] = {};
        __builtin_amdgcn_s_setprio(1);
        #pragma unroll
        for (int kd = 0; kd < 4; ++kd) {
          bf16x8 kf[4];
          #pragma unroll
          for (int n = 0; n < 4; ++n) {
            int row = n*16 + l15;
            int off = (row << 8) | (((kd*4 + l4) ^ (row & 7)) << 4);
            kf[n] = *(const bf16x8*)((const char*)Ksb + off);
          }
          #pragma unroll
          for (int m = 0; m < 2; ++m)
            #pragma unroll
            for (int n = 0; n < 4; ++n)
              sacc[m][n] = __builtin_amdgcn_mfma_f32_16x16x32_bf16(qf[m][kd], kf[n], sacc[m][n], 0, 0, 0);
        }
        __builtin_amdgcn_s_setprio(0);

        if (st >= 2*qb) {
          #pragma unroll
          for (int n = 0; n < 4; ++n) {
            int ki = kv0 + n*16 + l15;
            #pragma unroll
            for (int m = 0; m < 2; ++m)
              #pragma unroll
              for (int r = 0; r < 4; ++r) {
                int qi = q0w + m*16 + l4*4 + r;
                if (ki > qi) sacc[m][n][r] = -1e30f;
              }
          }
        }

        float pr[2][4][4];
        #pragma unroll
        for (int m = 0; m < 2; ++m) {
          #pragma unroll
          for (int r = 0; r < 4; ++r) {
            float s0 = sacc[m][0][r], s1 = sacc[m][1][r];
            float s2 = sacc[m][2][r], s3 = sacc[m][3][r];
            float vm = fmaxf(fmaxf(s0, s1), fmaxf(s2, s3));
            vm = red16_max(vm);
            float mo = mrun[m][r];
            float mnew = fmaxf(mo, vm);
            float al = __expf(mo - mnew);
            float p0 = __expf(s0 - mnew), p1 = __expf(s1 - mnew);
            float p2 = __expf(s2 - mnew), p3 = __expf(s3 - mnew);
            float rs = red16_sum((p0 + p1) + (p2 + p3));
            mrun[m][r] = mnew;
            lrun[m][r] = lrun[m][r]*al + rs;
            #pragma unroll
            for (int dn = 0; dn < 8; ++dn) oacc[m][dn][r] *= al;
            pr[m][r][0] = p0; pr[m][r][1] = p1; pr[m][r][2] = p2; pr[m][r][3] = p3;
          }
        }

        #pragma unroll
        for (int kvh = 0; kvh < 2; ++kvh) {
          #pragma unroll
          for (int m = 0; m < 2; ++m)
            #pragma unroll
            for (int nn = 0; nn < 2; ++nn) {
              int n = kvh*2 + nn;
              bf16x4 w4;
              w4[0] = (__bf16)pr[m][0][n]; w4[1] = (__bf16)pr[m][1][n];
              w4[2] = (__bf16)pr[m][2][n]; w4[3] = (__bf16)pr[m][3][n];
              *(bf16x4*)((char*)Pw + ((nn*4 + (l15 >> 2))*2 + m)*128
                                   + (l15 & 3)*32 + l4*8) = w4;
            }
          const char* pb = (const char*)Pw + l4*512 + l15*8;
          bf16x4 a00 = tr16(pb);
          bf16x4 a01 = tr16(pb + 256);
          bf16x4 a10 = tr16(pb + 128);
          bf16x4 a11 = tr16(pb + 384);
          const char* vb = (const char*)Vsb + l4*2048 + l15*8 + kvh*8192;
          bf16x4 b0[8], b1[8];
          #pragma unroll
          for (int dn = 0; dn < 8; ++dn) {
            b0[dn] = tr16(vb + dn*128);
            b1[dn] = tr16(vb + dn*128 + 1024);
          }
          WAIT_LGKM0; SGB0;
          bf16x8 pa0 = __builtin_shufflevector(a00, a01, 0,1,2,3,4,5,6,7);
          bf16x8 pa1 = __builtin_shufflevector(a10, a11, 0,1,2,3,4,5,6,7);
          __builtin_amdgcn_s_setprio(1);
          #pragma unroll
          for (int dn = 0; dn < 8; ++dn) {
            bf16x8 v8 = __builtin_shufflevector(b0[dn], b1[dn], 0,1,2,3,4,5,6,7);
            oacc[0][dn] = __builtin_amdgcn_mfma_f32_16x16x32_bf16(pa0, v8, oacc[0][dn], 0, 0, 0);
            oacc[1][dn] = __builtin_amdgcn_mfma_f32_16x16x32_bf16(pa1, v8, oacc[1][dn], 0, 0, 0);
          }
          __builtin_amdgcn_s_setprio(0);
        }
      }

      WAIT_VM0;
      __builtin_amdgcn_s_barrier();
      SGB0;
    }

    const size_t obase = ((size_t)(b*SS + q0w)) * DIM + h*HD;
    #pragma unroll
    for (int m = 0; m < 2; ++m) {
      #pragma unroll
      for (int r = 0; r < 4; ++r) {
        float inv = 1.0f / lrun[m][r];
        int srow = m*16 + l4*4 + r;
        #pragma unroll
        for (int dn = 0; dn < 8; ++dn)
          O[obase + (size_t)srow*DIM + dn*16 + l15] = f2bf(oacc[m][dn][r] * inv);
      }
    }
  }
}

extern "C" void kernel_launch(void* const* d_in, const int* in_sizes, int n_in,
                              void* d_out, int out_size, void* d_ws, size_t ws_size,
                              hipStream_t stream) {
  const float* x   = (const float*)d_in[0];
  const float* Wq  = (const float*)d_in[1];
  const float* Wkv = (const float*)d_in[2];
  const float* Wo  = (const float*)d_in[3];

  if (ws_size < (160ull << 20)) return;
  char* ws = (char*)d_ws;
  u16* xb   = (u16*)(ws);                  // 32 MB [4096][4096]
  u16* Wqb  = (u16*)(ws + (32ull  << 20)); // 32 MB [4096][4096]  \ fused W rows 0..6143
  u16* Wkvb = (u16*)(ws + (64ull  << 20)); // 16 MB [2048][4096]  /
  u16* Wob  = (u16*)(ws + (80ull  << 20)); // 32 MB [4096][4096]
  u16* QKVb = (u16*)(ws + (112ull << 20)); // 48 MB [4096][6144]
  u16* attnb = xb;                         // alias after projections

  // fp32 -> bf16, one launch (x | Wq | Wkv | Wo)
  f2b4_kernel<<<28672, 256, 0, stream>>>(x, Wq, Wkv, Wo, xb, Wqb, Wkvb, Wob);

  // fused QKV projection: [4096][6144] = xb @ [Wq;Wkv]^T ; QSCALE on Q cols only
  // grid 1536 = 2.0 rounds at 3 blocks/CU
  gemm128<0><<<dim3(32*48), 256, 0, stream>>>(xb, Wqb, QKVb,
                                              MROWS, QKVP, DIM, 48, DIM, QSCALE, 1.0f);

  attn_kernel<<<dim3(8, NHEADS, BB), 256, 0, stream>>>(QKVb, attnb);

  // output projection (fp32 out)
  gemm128<1><<<dim3(32*32), 256, 0, stream>>>(attnb, Wob, d_out,
                                              MROWS, DIM, DIM, 32, 0, 1.0f, 1.0f);
}

// Round 8
// 562.748 us; speedup vs baseline: 5.8518x; 1.1732x over previous
//
#include <hip/hip_runtime.h>

typedef __bf16 bf16x8 __attribute__((ext_vector_type(8)));
typedef __bf16 bf16x4 __attribute__((ext_vector_type(4)));
typedef float f32x4 __attribute__((ext_vector_type(4)));
typedef unsigned short u16;
typedef unsigned short u16x8 __attribute__((ext_vector_type(8)));

#define DIM 4096
#define NHEADS 32
#define NKV 8
#define HD 128
#define BB 2
#define SS 2048
#define MROWS (BB*SS)        // 4096
#define QKVP 6144            // fused QKV row pitch (4096 Q | 1024 K | 1024 V)
#define QSCALE 0.08838834764831843f  // 1/sqrt(128)

#define WAIT_LGKM0 asm volatile("s_waitcnt lgkmcnt(0)" ::: "memory")
#define WAIT_VM0   asm volatile("s_waitcnt vmcnt(0)" ::: "memory")
#define WAIT_VM4   asm volatile("s_waitcnt vmcnt(4)" ::: "memory")
#define WAIT_VM8   asm volatile("s_waitcnt vmcnt(8)" ::: "memory")
#define SGB0       __builtin_amdgcn_sched_barrier(0)

__device__ __forceinline__ u16 f2bf(float f) {
  unsigned int u = __float_as_uint(f);
  u += 0x7fffu + ((u >> 16) & 1u);   // round-to-nearest-even
  return (u16)(u >> 16);
}

__device__ __forceinline__ void gload16(const void* g, void* l) {
  __builtin_amdgcn_global_load_lds(
      (const __attribute__((address_space(1))) unsigned int*)g,
      (__attribute__((address_space(3))) unsigned int*)l, 16, 0, 0);
}

__device__ __forceinline__ bf16x4 tr16(const void* p) {
  bf16x4 d;
  asm volatile("ds_read_b64_tr_b16 %0, %1"
               : "=v"(d)
               : "v"((const __attribute__((address_space(3))) u16*)p)
               : "memory");
  return d;
}

template<int CTRL>
__device__ __forceinline__ float dpp_ror(float x) {
  return __int_as_float(__builtin_amdgcn_update_dpp(
      0, __float_as_int(x), CTRL, 0xF, 0xF, false));
}
__device__ __forceinline__ float red16_max(float v) {
  v = fmaxf(v, dpp_ror<0x121>(v));
  v = fmaxf(v, dpp_ror<0x122>(v));
  v = fmaxf(v, dpp_ror<0x124>(v));
  v = fmaxf(v, dpp_ror<0x128>(v));
  return v;
}
__device__ __forceinline__ float red16_sum(float v) {
  v += dpp_ror<0x121>(v);
  v += dpp_ror<0x122>(v);
  v += dpp_ror<0x124>(v);
  v += dpp_ror<0x128>(v);
  return v;
}

// ---------------- fp32 -> bf16 conversion, all 4 tensors in one launch ----------------
__global__ __launch_bounds__(256) void f2b4_kernel(
    const float* __restrict__ xa, const float* __restrict__ xb,
    const float* __restrict__ xc, const float* __restrict__ xd,
    u16* __restrict__ oa, u16* __restrict__ ob,
    u16* __restrict__ oc, u16* __restrict__ od) {
  int i = blockIdx.x * 256 + threadIdx.x;
  const float* in; u16* out; int k;
  if (i < 2097152)      { in = xa; out = oa; k = i; }
  else if (i < 4194304) { in = xb; out = ob; k = i - 2097152; }
  else if (i < 5242880) { in = xc; out = oc; k = i - 4194304; }
  else                  { in = xd; out = od; k = i - 5242880; }
  const float4* in4 = (const float4*)in;
  float4 a = in4[2*(size_t)k];
  float4 b = in4[2*(size_t)k + 1];
  u16x8 o;
  o[0]=f2bf(a.x); o[1]=f2bf(a.y); o[2]=f2bf(a.z); o[3]=f2bf(a.w);
  o[4]=f2bf(b.x); o[5]=f2bf(b.y); o[6]=f2bf(b.z); o[7]=f2bf(b.w);
  ((u16x8*)out)[k] = o;
}

// ---------------- 256x256 / BK=32 / 8-wave GEMM, C = A @ B^T ----------------
// R5 structure (best measured: QKV 792 TF) + per-XCD K-rotation: block starts
// its K loop at tile srot = (bid&7) * nt/8. Mechanism: de-synchronizes the 8
// XCD groups' HBM request phases (burst -> steady stream) while preserving
// intra-XCD A-panel L2 sharing exactly (same-bid&7 blocks keep equal phase).
// Accumulation over K is order-invariant. 4-deep K-tile ring (4 x 32KB LDS),
// counted vmcnt(8) checkpoints (never 0 mid-loop). Fine 2-phase interleave per
// K-tile: each phase {ds_read_b128 x4-8 ; 2 global_load_lds ; barrier ; lgkm0 ;
// 16-MFMA cluster ; barrier}. LDS per buf: ldsrow j holds tile rows {2j,2j+1};
// stored 16B-chunk c = src chunk ^ (j&7) (both-sides swizzle, rule 21).
template<int OUTF32>
__global__ __launch_bounds__(512, 2) void gemm256(
    const u16* __restrict__ A, const u16* __restrict__ Bm, void* __restrict__ C,
    int M, int N, int K, int nbx, int acut, float a0, float a1) {
  __shared__ char smem[131072];           // A: 4x16KB @0, B: 4x16KB @65536

  const int t = threadIdx.x;
  const int l = t & 63, w = t >> 6;
  const int l15 = l & 15, l4 = l >> 4;
  const int wm = w >> 2, wn = w & 3;      // 2 x 4 wave grid

  // bijective XCD swizzle (nwg % 8 == 0 for all our grids)
  const int nwg = gridDim.x;
  const int cpx = nwg >> 3;
  const int sw = (blockIdx.x & 7) * cpx + (blockIdx.x >> 3);
  const int bx = sw % nbx, by = sw / nbx;
  const int row0 = by * 256, col0 = bx * 256;
  const float alpha = (col0 < acut) ? a0 : a1;

  const int nt = K >> 5;                  // K-tiles of 32
  const int srot = (blockIdx.x & 7) * (nt >> 3);   // per-XCD K-phase rotation

  f32x4 acc[8][4] = {};

  auto stageM = [&](const u16* Mp, int base0, int bsel, int ktile) {
    const int k0 = ktile << 5;
    char* Md = smem + base0 + bsel * 16384;
    #pragma unroll
    for (int i = 0; i < 2; ++i) {
      int o = (i*8 + w)*64 + l;           // 16B-unit index in [0,1024)
      int j = o >> 3;                     // ldsrow
      int cs = (o & 7) ^ (j & 7);         // inverse-swizzled source chunk
      int r = 2*j + (cs >> 2);            // tile row
      int kc = (cs & 3) * 8;              // k element offset
      gload16((const char*)Mp + ((size_t)(base0 ? col0 + r : row0 + r)*K + k0 + kc)*2,
              Md + (i*8 + w)*1024);
    }
  };

  auto ldA = [&](const char* Ab, int mi) -> bf16x8 {
    int r = wm*128 + mi*16 + l15;
    int j = r >> 1;
    int c = ((r & 1)*4 + l4) ^ (j & 7);
    return *(const bf16x8*)(Ab + j*128 + c*16);
  };
  auto ldB = [&](const char* Bb, int ni) -> bf16x8 {
    int r = wn*64 + ni*16 + l15;
    int j = r >> 1;
    int c = ((r & 1)*4 + l4) ^ (j & 7);
    return *(const bf16x8*)(Bb + j*128 + c*16);
  };

  auto rot = [&](int i) -> int {
    int k = i + srot;
    return (k >= nt) ? k - nt : k;
  };

  stageM(A, 0, 0, rot(0)); stageM(Bm, 65536, 0, rot(0));
  stageM(A, 0, 1, rot(1)); stageM(Bm, 65536, 1, rot(1));
  stageM(A, 0, 2, rot(2)); stageM(Bm, 65536, 2, rot(2));
  WAIT_VM8;                               // tile 0 landed (own loads) ...
  __builtin_amdgcn_s_barrier();           // ... and everyone else's

  for (int i = 0; i < nt; ++i) {
    const char* Ab = smem + (i & 3) * 16384;
    const char* Bb = smem + 65536 + (i & 3) * 16384;
    const bool pf = (i + 3 < nt);
    const int pbuf = (i + 3) & 3;
    const int ptile = pf ? rot(i + 3) : 0;

    // ---- phase 0: ds(af0-3, bf0-3) | stage A(i+3) | 16 MFMA ----
    bf16x8 af0 = ldA(Ab, 0), af1 = ldA(Ab, 1), af2 = ldA(Ab, 2), af3 = ldA(Ab, 3);
    bf16x8 bf0 = ldB(Bb, 0), bf1 = ldB(Bb, 1), bf2 = ldB(Bb, 2), bf3 = ldB(Bb, 3);
    SGB0;
    if (pf) stageM(A, 0, pbuf, ptile);
    __builtin_amdgcn_s_barrier();
    WAIT_LGKM0; SGB0;
    __builtin_amdgcn_s_setprio(1);
    acc[0][0] = __builtin_amdgcn_mfma_f32_16x16x32_bf16(af0, bf0, acc[0][0], 0, 0, 0);
    acc[0][1] = __builtin_amdgcn_mfma_f32_16x16x32_bf16(af0, bf1, acc[0][1], 0, 0, 0);
    acc[0][2] = __builtin_amdgcn_mfma_f32_16x16x32_bf16(af0, bf2, acc[0][2], 0, 0, 0);
    acc[0][3] = __builtin_amdgcn_mfma_f32_16x16x32_bf16(af0, bf3, acc[0][3], 0, 0, 0);
    acc[1][0] = __builtin_amdgcn_mfma_f32_16x16x32_bf16(af1, bf0, acc[1][0], 0, 0, 0);
    acc[1][1] = __builtin_amdgcn_mfma_f32_16x16x32_bf16(af1, bf1, acc[1][1], 0, 0, 0);
    acc[1][2] = __builtin_amdgcn_mfma_f32_16x16x32_bf16(af1, bf2, acc[1][2], 0, 0, 0);
    acc[1][3] = __builtin_amdgcn_mfma_f32_16x16x32_bf16(af1, bf3, acc[1][3], 0, 0, 0);
    acc[2][0] = __builtin_amdgcn_mfma_f32_16x16x32_bf16(af2, bf0, acc[2][0], 0, 0, 0);
    acc[2][1] = __builtin_amdgcn_mfma_f32_16x16x32_bf16(af2, bf1, acc[2][1], 0, 0, 0);
    acc[2][2] = __builtin_amdgcn_mfma_f32_16x16x32_bf16(af2, bf2, acc[2][2], 0, 0, 0);
    acc[2][3] = __builtin_amdgcn_mfma_f32_16x16x32_bf16(af2, bf3, acc[2][3], 0, 0, 0);
    acc[3][0] = __builtin_amdgcn_mfma_f32_16x16x32_bf16(af3, bf0, acc[3][0], 0, 0, 0);
    acc[3][1] = __builtin_amdgcn_mfma_f32_16x16x32_bf16(af3, bf1, acc[3][1], 0, 0, 0);
    acc[3][2] = __builtin_amdgcn_mfma_f32_16x16x32_bf16(af3, bf2, acc[3][2], 0, 0, 0);
    acc[3][3] = __builtin_amdgcn_mfma_f32_16x16x32_bf16(af3, bf3, acc[3][3], 0, 0, 0);
    __builtin_amdgcn_s_setprio(0);
    __builtin_amdgcn_s_barrier();

    // ---- phase 1: ds(af4-7) | stage B(i+3) | 16 MFMA | counted vmcnt ----
    bf16x8 af4 = ldA(Ab, 4), af5 = ldA(Ab, 5), af6 = ldA(Ab, 6), af7 = ldA(Ab, 7);
    SGB0;
    if (pf) stageM(Bm, 65536, pbuf, ptile);
    __builtin_amdgcn_s_barrier();
    WAIT_LGKM0; SGB0;
    __builtin_amdgcn_s_setprio(1);
    acc[4][0] = __builtin_amdgcn_mfma_f32_16x16x32_bf16(af4, bf0, acc[4][0], 0, 0, 0);
    acc[4][1] = __builtin_amdgcn_mfma_f32_16x16x32_bf16(af4, bf1, acc[4][1], 0, 0, 0);
    acc[4][2] = __builtin_amdgcn_mfma_f32_16x16x32_bf16(af4, bf2, acc[4][2], 0, 0, 0);
    acc[4][3] = __builtin_amdgcn_mfma_f32_16x16x32_bf16(af4, bf3, acc[4][3], 0, 0, 0);
    acc[5][0] = __builtin_amdgcn_mfma_f32_16x16x32_bf16(af5, bf0, acc[5][0], 0, 0, 0);
    acc[5][1] = __builtin_amdgcn_mfma_f32_16x16x32_bf16(af5, bf1, acc[5][1], 0, 0, 0);
    acc[5][2] = __builtin_amdgcn_mfma_f32_16x16x32_bf16(af5, bf2, acc[5][2], 0, 0, 0);
    acc[5][3] = __builtin_amdgcn_mfma_f32_16x16x32_bf16(af5, bf3, acc[5][3], 0, 0, 0);
    acc[6][0] = __builtin_amdgcn_mfma_f32_16x16x32_bf16(af6, bf0, acc[6][0], 0, 0, 0);
    acc[6][1] = __builtin_amdgcn_mfma_f32_16x16x32_bf16(af6, bf1, acc[6][1], 0, 0, 0);
    acc[6][2] = __builtin_amdgcn_mfma_f32_16x16x32_bf16(af6, bf2, acc[6][2], 0, 0, 0);
    acc[6][3] = __builtin_amdgcn_mfma_f32_16x16x32_bf16(af6, bf3, acc[6][3], 0, 0, 0);
    acc[7][0] = __builtin_amdgcn_mfma_f32_16x16x32_bf16(af7, bf0, acc[7][0], 0, 0, 0);
    acc[7][1] = __builtin_amdgcn_mfma_f32_16x16x32_bf16(af7, bf1, acc[7][1], 0, 0, 0);
    acc[7][2] = __builtin_amdgcn_mfma_f32_16x16x32_bf16(af7, bf2, acc[7][2], 0, 0, 0);
    acc[7][3] = __builtin_amdgcn_mfma_f32_16x16x32_bf16(af7, bf3, acc[7][3], 0, 0, 0);
    __builtin_amdgcn_s_setprio(0);
    // boundary checkpoint: force tile i+1 landed; keep i+2/i+3 in flight
    if (pf)               { WAIT_VM8; }
    else if (i + 2 < nt)  { WAIT_VM4; }
    else if (i + 1 < nt)  { WAIT_VM0; }
    __builtin_amdgcn_s_barrier();
  }

  // epilogue: C/D layout col=lane&15, row=(lane>>4)*4+reg
  #pragma unroll
  for (int mi = 0; mi < 8; ++mi) {
    #pragma unroll
    for (int ni = 0; ni < 4; ++ni) {
      #pragma unroll
      for (int r = 0; r < 4; ++r) {
        size_t rr = (size_t)(row0 + wm*128 + mi*16 + l4*4 + r);
        size_t cc = (size_t)(col0 + wn*64 + ni*16 + l15);
        float v = acc[mi][ni][r] * alpha;
        if (OUTF32) ((float*)C)[rr*(size_t)N + cc] = v;
        else        ((u16*)C)[rr*(size_t)N + cc] = f2bf(v);
      }
    }
  }
}

// ---------------- causal GQA flash attention (QKVP pitch) ----------------
__global__ __launch_bounds__(256, 2) void attn_kernel(
    const u16* __restrict__ QKV,  // [4096][6144]: 0..4095 Q | 4096..5119 K | 5120..6143 V
    u16* __restrict__ O) {        // [4096][4096]
  __shared__ u16 Ks[2][64*128];
  __shared__ u16 Vs[2][64*128];
  __shared__ u16 Ps[4][1024];
  const int t = threadIdx.x;
  const int l = t & 63, w = t >> 6;
  const int l15 = l & 15, l4 = l >> 4;
  const int pair = blockIdx.x, h = blockIdx.y, b = blockIdx.z;
  const int hkv = h >> 2;
  const u16* Kg = QKV + (size_t)(b*SS) * QKVP + DIM + hkv*HD;
  const u16* Vg = Kg + NKV*HD;
  u16* Pw = &Ps[w][0];

  auto stage = [&](u16* Ksb, u16* Vsb, int kv0) {
    const u16* Kr = Kg + (size_t)kv0 * QKVP;
    const u16* Vr = Vg + (size_t)kv0 * QKVP;
    #pragma unroll
    for (int i = 0; i < 4; ++i) {
      int o = i*4096 + w*1024 + l*16;
      int row = o >> 8;
      int sc = l15 ^ (row & 7);
      gload16((const char*)(Kr + (size_t)row * QKVP) + sc*16,
              (char*)Ksb + i*4096 + w*1024);
    }
    #pragma unroll
    for (int i = 0; i < 4; ++i) {
      int cb = i*4 + w;
      int kv = cb*4 + ((l & 7) >> 1);
      int d0 = ((l >> 3) << 4) + (l & 1)*8;
      gload16((const char*)(Vr + (size_t)kv * QKVP + d0),
              (char*)Vsb + cb*1024);
    }
  };

  for (int half = 0; half < 2; ++half) {
    const int qb = half ? (15 - pair) : pair;
    const int q0 = qb * 128;
    const int q0w = q0 + w*32;

    const size_t qbase = ((size_t)(b*SS + q0w)) * QKVP + h*HD;
    bf16x8 qf[2][4];
    #pragma unroll
    for (int m = 0; m < 2; ++m)
      #pragma unroll
      for (int kd = 0; kd < 4; ++kd)
        qf[m][kd] = *(const bf16x8*)&QKV[qbase + (size_t)(m*16 + l15)*QKVP + kd*32 + l4*8];

    f32x4 oacc[2][8] = {};
    float mrun[2][4], lrun[2][4];
    #pragma unroll
    for (int m = 0; m < 2; ++m)
      #pragma unroll
      for (int r = 0; r < 4; ++r) { mrun[m][r] = -1e30f; lrun[m][r] = 0.f; }

    const int nst = 2*qb + 2;
    stage(Ks[0], Vs[0], 0);
    WAIT_VM0;
    __builtin_amdgcn_s_barrier();
    SGB0;

    for (int st = 0; st < nst; ++st) {
      const int kv0 = st * 64;
      u16* Ksb = Ks[st & 1];
      u16* Vsb = Vs[st & 1];
      if (st + 1 < nst) stage(Ks[(st+1) & 1], Vs[(st+1) & 1], kv0 + 64);

      if (kv0 <= q0w + 31) {
        f32x4 sacc[2][4] = {};
        __builtin_amdgcn_s_setprio(1);
        #pragma unroll
        for (int kd = 0; kd < 4; ++kd) {
          bf16x8 kf[4];
          #pragma unroll
          for (int n = 0; n < 4; ++n) {
            int row = n*16 + l15;
            int off = (row << 8) | (((kd*4 + l4) ^ (row & 7)) << 4);
            kf[n] = *(const bf16x8*)((const char*)Ksb + off);
          }
          #pragma unroll
          for (int m = 0; m < 2; ++m)
            #pragma unroll
            for (int n = 0; n < 4; ++n)
              sacc[m][n] = __builtin_amdgcn_mfma_f32_16x16x32_bf16(qf[m][kd], kf[n], sacc[m][n], 0, 0, 0);
        }
        __builtin_amdgcn_s_setprio(0);

        if (st >= 2*qb) {
          #pragma unroll
          for (int n = 0; n < 4; ++n) {
            int ki = kv0 + n*16 + l15;
            #pragma unroll
            for (int m = 0; m < 2; ++m)
              #pragma unroll
              for (int r = 0; r < 4; ++r) {
                int qi = q0w + m*16 + l4*4 + r;
                if (ki > qi) sacc[m][n][r] = -1e30f;
              }
          }
        }

        float pr[2][4][4];
        #pragma unroll
        for (int m = 0; m < 2; ++m) {
          #pragma unroll
          for (int r = 0; r < 4; ++r) {
            float s0 = sacc[m][0][r], s1 = sacc[m][1][r];
            float s2 = sacc[m][2][r], s3 = sacc[m][3][r];
            float vm = fmaxf(fmaxf(s0, s1), fmaxf(s2, s3));
            vm = red16_max(vm);
            float mo = mrun[m][r];
            float mnew = fmaxf(mo, vm);
            float al = __expf(mo - mnew);
            float p0 = __expf(s0 - mnew), p1 = __expf(s1 - mnew);
            float p2 = __expf(s2 - mnew), p3 = __expf(s3 - mnew);
            float rs = red16_sum((p0 + p1) + (p2 + p3));
            mrun[m][r] = mnew;
            lrun[m][r] = lrun[m][r]*al + rs;
            #pragma unroll
            for (int dn = 0; dn < 8; ++dn) oacc[m][dn][r] *= al;
            pr[m][r][0] = p0; pr[m][r][1] = p1; pr[m][r][2] = p2; pr[m][r][3] = p3;
          }
        }

        #pragma unroll
        for (int kvh = 0; kvh < 2; ++kvh) {
          #pragma unroll
          for (int m = 0; m < 2; ++m)
            #pragma unroll
            for (int nn = 0; nn < 2; ++nn) {
              int n = kvh*2 + nn;
              bf16x4 w4;
              w4[0] = (__bf16)pr[m][0][n]; w4[1] = (__bf16)pr[m][1][n];
              w4[2] = (__bf16)pr[m][2][n]; w4[3] = (__bf16)pr[m][3][n];
              *(bf16x4*)((char*)Pw + ((nn*4 + (l15 >> 2))*2 + m)*128
                                   + (l15 & 3)*32 + l4*8) = w4;
            }
          const char* pb = (const char*)Pw + l4*512 + l15*8;
          bf16x4 a00 = tr16(pb);
          bf16x4 a01 = tr16(pb + 256);
          bf16x4 a10 = tr16(pb + 128);
          bf16x4 a11 = tr16(pb + 384);
          const char* vb = (const char*)Vsb + l4*2048 + l15*8 + kvh*8192;
          bf16x4 b0[8], b1[8];
          #pragma unroll
          for (int dn = 0; dn < 8; ++dn) {
            b0[dn] = tr16(vb + dn*128);
            b1[dn] = tr16(vb + dn*128 + 1024);
          }
          WAIT_LGKM0; SGB0;
          bf16x8 pa0 = __builtin_shufflevector(a00, a01, 0,1,2,3,4,5,6,7);
          bf16x8 pa1 = __builtin_shufflevector(a10, a11, 0,1,2,3,4,5,6,7);
          __builtin_amdgcn_s_setprio(1);
          #pragma unroll
          for (int dn = 0; dn < 8; ++dn) {
            bf16x8 v8 = __builtin_shufflevector(b0[dn], b1[dn], 0,1,2,3,4,5,6,7);
            oacc[0][dn] = __builtin_amdgcn_mfma_f32_16x16x32_bf16(pa0, v8, oacc[0][dn], 0, 0, 0);
            oacc[1][dn] = __builtin_amdgcn_mfma_f32_16x16x32_bf16(pa1, v8, oacc[1][dn], 0, 0, 0);
          }
          __builtin_amdgcn_s_setprio(0);
        }
      }

      WAIT_VM0;
      __builtin_amdgcn_s_barrier();
      SGB0;
    }

    const size_t obase = ((size_t)(b*SS + q0w)) * DIM + h*HD;
    #pragma unroll
    for (int m = 0; m < 2; ++m) {
      #pragma unroll
      for (int r = 0; r < 4; ++r) {
        float inv = 1.0f / lrun[m][r];
        int srow = m*16 + l4*4 + r;
        #pragma unroll
        for (int dn = 0; dn < 8; ++dn)
          O[obase + (size_t)srow*DIM + dn*16 + l15] = f2bf(oacc[m][dn][r] * inv);
      }
    }
  }
}

extern "C" void kernel_launch(void* const* d_in, const int* in_sizes, int n_in,
                              void* d_out, int out_size, void* d_ws, size_t ws_size,
                              hipStream_t stream) {
  const float* x   = (const float*)d_in[0];
  const float* Wq  = (const float*)d_in[1];
  const float* Wkv = (const float*)d_in[2];
  const float* Wo  = (const float*)d_in[3];

  if (ws_size < (160ull << 20)) return;
  char* ws = (char*)d_ws;
  u16* xb   = (u16*)(ws);                  // 32 MB [4096][4096]
  u16* Wqb  = (u16*)(ws + (32ull  << 20)); // 32 MB [4096][4096]  \ fused W rows 0..6143
  u16* Wkvb = (u16*)(ws + (64ull  << 20)); // 16 MB [2048][4096]  /
  u16* Wob  = (u16*)(ws + (80ull  << 20)); // 32 MB [4096][4096]
  u16* QKVb = (u16*)(ws + (112ull << 20)); // 48 MB [4096][6144]
  u16* attnb = xb;                         // alias after projections

  // fp32 -> bf16, one launch (x | Wq | Wkv | Wo)
  f2b4_kernel<<<28672, 256, 0, stream>>>(x, Wq, Wkv, Wo, xb, Wqb, Wkvb, Wob);

  // fused QKV projection: [4096][6144] = xb @ [Wq;Wkv]^T ; QSCALE on Q cols only
  gemm256<0><<<dim3(16*24), 512, 0, stream>>>(xb, Wqb, QKVb,
                                              MROWS, QKVP, DIM, 24, DIM, QSCALE, 1.0f);

  attn_kernel<<<dim3(8, NHEADS, BB), 256, 0, stream>>>(QKVb, attnb);

  // output projection (fp32 out)
  gemm256<1><<<dim3(16*16), 512, 0, stream>>>(attnb, Wob, d_out,
                                              MROWS, DIM, DIM, 16, 0, 1.0f, 1.0f);
}

// Round 9
// 543.560 us; speedup vs baseline: 6.0583x; 1.0353x over previous
//
#include <hip/hip_runtime.h>

typedef __bf16 bf16x8 __attribute__((ext_vector_type(8)));
typedef __bf16 bf16x4 __attribute__((ext_vector_type(4)));
typedef float f32x4 __attribute__((ext_vector_type(4)));
typedef unsigned short u16;
typedef unsigned short u16x8 __attribute__((ext_vector_type(8)));

#define DIM 4096
#define NHEADS 32
#define NKV 8
#define HD 128
#define BB 2
#define SS 2048
#define MROWS (BB*SS)        // 4096
#define QKVP 6144            // fused QKV row pitch (4096 Q | 1024 K | 1024 V)
#define QSCALE 0.08838834764831843f  // 1/sqrt(128)

#define WAIT_LGKM0 asm volatile("s_waitcnt lgkmcnt(0)" ::: "memory")
#define WAIT_VM0   asm volatile("s_waitcnt vmcnt(0)" ::: "memory")
#define WAIT_VM4   asm volatile("s_waitcnt vmcnt(4)" ::: "memory")
#define SGB0       __builtin_amdgcn_sched_barrier(0)

__device__ __forceinline__ u16 f2bf(float f) {
  unsigned int u = __float_as_uint(f);
  u += 0x7fffu + ((u >> 16) & 1u);   // round-to-nearest-even
  return (u16)(u >> 16);
}

__device__ __forceinline__ void gload16(const void* g, void* l) {
  __builtin_amdgcn_global_load_lds(
      (const __attribute__((address_space(1))) unsigned int*)g,
      (__attribute__((address_space(3))) unsigned int*)l, 16, 0, 0);
}

__device__ __forceinline__ bf16x4 tr16(const void* p) {
  bf16x4 d;
  asm volatile("ds_read_b64_tr_b16 %0, %1"
               : "=v"(d)
               : "v"((const __attribute__((address_space(3))) u16*)p)
               : "memory");
  return d;
}

template<int CTRL>
__device__ __forceinline__ float dpp_ror(float x) {
  return __int_as_float(__builtin_amdgcn_update_dpp(
      0, __float_as_int(x), CTRL, 0xF, 0xF, false));
}
__device__ __forceinline__ float red16_max(float v) {
  v = fmaxf(v, dpp_ror<0x121>(v));
  v = fmaxf(v, dpp_ror<0x122>(v));
  v = fmaxf(v, dpp_ror<0x124>(v));
  v = fmaxf(v, dpp_ror<0x128>(v));
  return v;
}
__device__ __forceinline__ float red16_sum(float v) {
  v += dpp_ror<0x121>(v);
  v += dpp_ror<0x122>(v);
  v += dpp_ror<0x124>(v);
  v += dpp_ror<0x128>(v);
  return v;
}

// ---------------- fp32 -> bf16 conversion, all 4 tensors in one launch ----------------
__global__ __launch_bounds__(256) void f2b4_kernel(
    const float* __restrict__ xa, const float* __restrict__ xb,
    const float* __restrict__ xc, const float* __restrict__ xd,
    u16* __restrict__ oa, u16* __restrict__ ob,
    u16* __restrict__ oc, u16* __restrict__ od) {
  int i = blockIdx.x * 256 + threadIdx.x;
  const float* in; u16* out; int k;
  if (i < 2097152)      { in = xa; out = oa; k = i; }
  else if (i < 4194304) { in = xb; out = ob; k = i - 2097152; }
  else if (i < 5242880) { in = xc; out = oc; k = i - 4194304; }
  else                  { in = xd; out = od; k = i - 5242880; }
  const float4* in4 = (const float4*)in;
  float4 a = in4[2*(size_t)k];
  float4 b = in4[2*(size_t)k + 1];
  u16x8 o;
  o[0]=f2bf(a.x); o[1]=f2bf(a.y); o[2]=f2bf(a.z); o[3]=f2bf(a.w);
  o[4]=f2bf(b.x); o[5]=f2bf(b.y); o[6]=f2bf(b.z); o[7]=f2bf(b.w);
  ((u16x8*)out)[k] = o;
}

// ---------------- 256x256 / BK=32 / 8-wave GEMM, C = A @ B^T ----------------
// Register-level fragment double-buffer: per K-tile i, issue stage(i+3) +
// 12 ds_reads for tile i+1 into the OTHER frag set, then run tile i's 32 MFMA
// from already-waited regs (DS pipe drains UNDER the MFMA cluster), then
// lgkm0 + counted vmcnt(4) + one barrier. Hazards: reads of tile i+1 covered
// by prev iter's vmcnt(4); stage(i+3) overwrites buf (i-1)&3 whose reads
// retired 2 barriers ago. 4-deep K-tile ring (4x16KB per matrix). LDS: ldsrow
// j holds tile rows {2j,2j+1}; stored 16B-chunk c = src ^ (j&7) (rule 21).
// Frag offsets: swizzle is mi-invariant -> off(mi) = off0 + mi*1024 (imm).
template<int OUTF32>
__global__ __launch_bounds__(512, 2) void gemm256(
    const u16* __restrict__ A, const u16* __restrict__ Bm, void* __restrict__ C,
    int M, int N, int K, int nbx, int acut, float a0, float a1) {
  __shared__ char smem[131072];           // A: 4x16KB @0, B: 4x16KB @65536

  const int t = threadIdx.x;
  const int l = t & 63, w = t >> 6;
  const int l15 = l & 15, l4 = l >> 4;
  const int wm = w >> 2, wn = w & 3;      // 2 x 4 wave grid, 128x64 per wave

  // bijective XCD swizzle (nwg % 8 == 0 for all our grids)
  const int nwg = gridDim.x;
  const int cpx = nwg >> 3;
  const int sw = (blockIdx.x & 7) * cpx + (blockIdx.x >> 3);
  const int bx = sw % nbx, by = sw / nbx;
  const int row0 = by * 256, col0 = bx * 256;
  const float alpha = (col0 < acut) ? a0 : a1;

  f32x4 acc[8][4] = {};

  // ---- stage addressing (pointer-increment, 64B per K-tile) ----
  // 1024 16B-units per matrix-tile; thread t covers units t and t+512.
  int ro0, ko0, ro1, ko1;
  {
    int o = t, j = o >> 3, cs = (o & 7) ^ (j & 7);
    ro0 = 2*j + (cs >> 2); ko0 = (cs & 3) * 8;
    o = t + 512; j = o >> 3; cs = (o & 7) ^ (j & 7);
    ro1 = 2*j + (cs >> 2); ko1 = (cs & 3) * 8;
  }
  const char* gA0 = (const char*)(A  + (size_t)(row0 + ro0) * K + ko0);
  const char* gA1 = (const char*)(A  + (size_t)(row0 + ro1) * K + ko1);
  const char* gB0 = (const char*)(Bm + (size_t)(col0 + ro0) * K + ko0);
  const char* gB1 = (const char*)(Bm + (size_t)(col0 + ro1) * K + ko1);

  auto stage = [&](int bsel) {
    char* Ad = (char*)smem + bsel * 16384;
    char* Bd = Ad + 65536;
    gload16(gA0, Ad + w*1024);
    gload16(gA1, Ad + 8192 + w*1024);
    gload16(gB0, Bd + w*1024);
    gload16(gB1, Bd + 8192 + w*1024);
    gA0 += 64; gA1 += 64; gB0 += 64; gB1 += 64;
  };

  // ---- fragment offsets (mi/ni-invariant swizzle: step = 1024 B) ----
  int offA0, offB0;
  {
    int r = wm*128 + l15, j = r >> 1;
    int c = ((r & 1)*4 + l4) ^ (j & 7);
    offA0 = j*128 + c*16;
    r = wn*64 + l15; j = r >> 1;
    c = ((r & 1)*4 + l4) ^ (j & 7);
    offB0 = 65536 + j*128 + c*16;
  }

  struct Frags { bf16x8 a0,a1,a2,a3,a4,a5,a6,a7,b0,b1,b2,b3; };
  Frags F0, F1;

  auto loadF = [&](Frags& F, int bsel) {
    const char* Sb = (const char*)smem + bsel * 16384;
    const char* Ab = Sb + offA0;
    const char* Bb = Sb + offB0;
    F.a0 = *(const bf16x8*)(Ab);
    F.a1 = *(const bf16x8*)(Ab + 1024);
    F.a2 = *(const bf16x8*)(Ab + 2048);
    F.a3 = *(const bf16x8*)(Ab + 3072);
    F.a4 = *(const bf16x8*)(Ab + 4096);
    F.a5 = *(const bf16x8*)(Ab + 5120);
    F.a6 = *(const bf16x8*)(Ab + 6144);
    F.a7 = *(const bf16x8*)(Ab + 7168);
    F.b0 = *(const bf16x8*)(Bb);
    F.b1 = *(const bf16x8*)(Bb + 1024);
    F.b2 = *(const bf16x8*)(Bb + 2048);
    F.b3 = *(const bf16x8*)(Bb + 3072);
  };

  auto mfmaC = [&](const Frags& F) {
    __builtin_amdgcn_s_setprio(1);
    acc[0][0] = __builtin_amdgcn_mfma_f32_16x16x32_bf16(F.a0, F.b0, acc[0][0], 0, 0, 0);
    acc[0][1] = __builtin_amdgcn_mfma_f32_16x16x32_bf16(F.a0, F.b1, acc[0][1], 0, 0, 0);
    acc[0][2] = __builtin_amdgcn_mfma_f32_16x16x32_bf16(F.a0, F.b2, acc[0][2], 0, 0, 0);
    acc[0][3] = __builtin_amdgcn_mfma_f32_16x16x32_bf16(F.a0, F.b3, acc[0][3], 0, 0, 0);
    acc[1][0] = __builtin_amdgcn_mfma_f32_16x16x32_bf16(F.a1, F.b0, acc[1][0], 0, 0, 0);
    acc[1][1] = __builtin_amdgcn_mfma_f32_16x16x32_bf16(F.a1, F.b1, acc[1][1], 0, 0, 0);
    acc[1][2] = __builtin_amdgcn_mfma_f32_16x16x32_bf16(F.a1, F.b2, acc[1][2], 0, 0, 0);
    acc[1][3] = __builtin_amdgcn_mfma_f32_16x16x32_bf16(F.a1, F.b3, acc[1][3], 0, 0, 0);
    acc[2][0] = __builtin_amdgcn_mfma_f32_16x16x32_bf16(F.a2, F.b0, acc[2][0], 0, 0, 0);
    acc[2][1] = __builtin_amdgcn_mfma_f32_16x16x32_bf16(F.a2, F.b1, acc[2][1], 0, 0, 0);
    acc[2][2] = __builtin_amdgcn_mfma_f32_16x16x32_bf16(F.a2, F.b2, acc[2][2], 0, 0, 0);
    acc[2][3] = __builtin_amdgcn_mfma_f32_16x16x32_bf16(F.a2, F.b3, acc[2][3], 0, 0, 0);
    acc[3][0] = __builtin_amdgcn_mfma_f32_16x16x32_bf16(F.a3, F.b0, acc[3][0], 0, 0, 0);
    acc[3][1] = __builtin_amdgcn_mfma_f32_16x16x32_bf16(F.a3, F.b1, acc[3][1], 0, 0, 0);
    acc[3][2] = __builtin_amdgcn_mfma_f32_16x16x32_bf16(F.a3, F.b2, acc[3][2], 0, 0, 0);
    acc[3][3] = __builtin_amdgcn_mfma_f32_16x16x32_bf16(F.a3, F.b3, acc[3][3], 0, 0, 0);
    acc[4][0] = __builtin_amdgcn_mfma_f32_16x16x32_bf16(F.a4, F.b0, acc[4][0], 0, 0, 0);
    acc[4][1] = __builtin_amdgcn_mfma_f32_16x16x32_bf16(F.a4, F.b1, acc[4][1], 0, 0, 0);
    acc[4][2] = __builtin_amdgcn_mfma_f32_16x16x32_bf16(F.a4, F.b2, acc[4][2], 0, 0, 0);
    acc[4][3] = __builtin_amdgcn_mfma_f32_16x16x32_bf16(F.a4, F.b3, acc[4][3], 0, 0, 0);
    acc[5][0] = __builtin_amdgcn_mfma_f32_16x16x32_bf16(F.a5, F.b0, acc[5][0], 0, 0, 0);
    acc[5][1] = __builtin_amdgcn_mfma_f32_16x16x32_bf16(F.a5, F.b1, acc[5][1], 0, 0, 0);
    acc[5][2] = __builtin_amdgcn_mfma_f32_16x16x32_bf16(F.a5, F.b2, acc[5][2], 0, 0, 0);
    acc[5][3] = __builtin_amdgcn_mfma_f32_16x16x32_bf16(F.a5, F.b3, acc[5][3], 0, 0, 0);
    acc[6][0] = __builtin_amdgcn_mfma_f32_16x16x32_bf16(F.a6, F.b0, acc[6][0], 0, 0, 0);
    acc[6][1] = __builtin_amdgcn_mfma_f32_16x16x32_bf16(F.a6, F.b1, acc[6][1], 0, 0, 0);
    acc[6][2] = __builtin_amdgcn_mfma_f32_16x16x32_bf16(F.a6, F.b2, acc[6][2], 0, 0, 0);
    acc[6][3] = __builtin_amdgcn_mfma_f32_16x16x32_bf16(F.a6, F.b3, acc[6][3], 0, 0, 0);
    acc[7][0] = __builtin_amdgcn_mfma_f32_16x16x32_bf16(F.a7, F.b0, acc[7][0], 0, 0, 0);
    acc[7][1] = __builtin_amdgcn_mfma_f32_16x16x32_bf16(F.a7, F.b1, acc[7][1], 0, 0, 0);
    acc[7][2] = __builtin_amdgcn_mfma_f32_16x16x32_bf16(F.a7, F.b2, acc[7][2], 0, 0, 0);
    acc[7][3] = __builtin_amdgcn_mfma_f32_16x16x32_bf16(F.a7, F.b3, acc[7][3], 0, 0, 0);
    __builtin_amdgcn_s_setprio(0);
  };

  const int nt = K >> 5;                  // K-tiles of 32 (even, >= 4)

  // prologue: 3 tiles in flight; tiles 0,1 landed; regs for tile 0 loaded
  stage(0); stage(1); stage(2);
  WAIT_VM4;
  __builtin_amdgcn_s_barrier();
  loadF(F0, 0);
  WAIT_LGKM0; SGB0;

  for (int i = 0; i < nt; i += 2) {
    {
      const bool pf = (i + 3 < nt);
      if (pf) stage((i + 3) & 3);
      if (i + 1 < nt) loadF(F1, (i + 1) & 3);
      SGB0;
      mfmaC(F0);
      SGB0;
      WAIT_LGKM0; SGB0;
      if (pf) { WAIT_VM4; } else { WAIT_VM0; }
      __builtin_amdgcn_s_barrier();
    }
    if (i + 1 < nt) {
      const bool pf = (i + 4 < nt);
      if (pf) stage((i + 4) & 3);
      if (i + 2 < nt) loadF(F0, (i + 2) & 3);
      SGB0;
      mfmaC(F1);
      SGB0;
      WAIT_LGKM0; SGB0;
      if (pf) { WAIT_VM4; } else { WAIT_VM0; }
      __builtin_amdgcn_s_barrier();
    }
  }

  // epilogue: C/D layout col=lane&15, row=(lane>>4)*4+reg
  #pragma unroll
  for (int mi = 0; mi < 8; ++mi) {
    #pragma unroll
    for (int ni = 0; ni < 4; ++ni) {
      #pragma unroll
      for (int r = 0; r < 4; ++r) {
        size_t rr = (size_t)(row0 + wm*128 + mi*16 + l4*4 + r);
        size_t cc = (size_t)(col0 + wn*64 + ni*16 + l15);
        float v = acc[mi][ni][r] * alpha;
        if (OUTF32) ((float*)C)[rr*(size_t)N + cc] = v;
        else        ((u16*)C)[rr*(size_t)N + cc] = f2bf(v);
      }
    }
  }
}

// ---------------- causal GQA flash attention (QKVP pitch) ----------------
__global__ __launch_bounds__(256, 2) void attn_kernel(
    const u16* __restrict__ QKV,  // [4096][6144]: 0..4095 Q | 4096..5119 K | 5120..6143 V
    u16* __restrict__ O) {        // [4096][4096]
  __shared__ u16 Ks[2][64*128];
  __shared__ u16 Vs[2][64*128];
  __shared__ u16 Ps[4][1024];
  const int t = threadIdx.x;
  const int l = t & 63, w = t >> 6;
  const int l15 = l & 15, l4 = l >> 4;
  const int pair = blockIdx.x, h = blockIdx.y, b = blockIdx.z;
  const int hkv = h >> 2;
  const u16* Kg = QKV + (size_t)(b*SS) * QKVP + DIM + hkv*HD;
  const u16* Vg = Kg + NKV*HD;
  u16* Pw = &Ps[w][0];

  auto stage = [&](u16* Ksb, u16* Vsb, int kv0) {
    const u16* Kr = Kg + (size_t)kv0 * QKVP;
    const u16* Vr = Vg + (size_t)kv0 * QKVP;
    #pragma unroll
    for (int i = 0; i < 4; ++i) {
      int o = i*4096 + w*1024 + l*16;
      int row = o >> 8;
      int sc = l15 ^ (row & 7);
      gload16((const char*)(Kr + (size_t)row * QKVP) + sc*16,
              (char*)Ksb + i*4096 + w*1024);
    }
    #pragma unroll
    for (int i = 0; i < 4; ++i) {
      int cb = i*4 + w;
      int kv = cb*4 + ((l & 7) >> 1);
      int d0 = ((l >> 3) << 4) + (l & 1)*8;
      gload16((const char*)(Vr + (size_t)kv * QKVP + d0),
              (char*)Vsb + cb*1024);
    }
  };

  for (int half = 0; half < 2; ++half) {
    const int qb = half ? (15 - pair) : pair;
    const int q0 = qb * 128;
    const int q0w = q0 + w*32;

    const size_t qbase = ((size_t)(b*SS + q0w)) * QKVP + h*HD;
    bf16x8 qf[2][4];
    #pragma unroll
    for (int m = 0; m < 2; ++m)
      #pragma unroll
      for (int kd = 0; kd < 4; ++kd)
        qf[m][kd] = *(const bf16x8*)&QKV[qbase + (size_t)(m*16 + l15)*QKVP + kd*32 + l4*8];

    f32x4 oacc[2][8] = {};
    float mrun[2][4], lrun[2][4];
    #pragma unroll
    for (int m = 0; m < 2; ++m)
      #pragma unroll
      for (int r = 0; r < 4; ++r) { mrun[m][r] = -1e30f; lrun[m][r] = 0.f; }

    const int nst = 2*qb + 2;
    stage(Ks[0], Vs[0], 0);
    WAIT_VM0;
    __builtin_amdgcn_s_barrier();
    SGB0;

    for (int st = 0; st < nst; ++st) {
      const int kv0 = st * 64;
      u16* Ksb = Ks[st & 1];
      u16* Vsb = Vs[st & 1];
      if (st + 1 < nst) stage(Ks[(st+1) & 1], Vs[(st+1) & 1], kv0 + 64);

      if (kv0 <= q0w + 31) {
        f32x4 sacc[2][4] = {};
        __builtin_amdgcn_s_setprio(1);
        #pragma unroll
        for (int kd = 0; kd < 4; ++kd) {
          bf16x8 kf[4];
          #pragma unroll
          for (int n = 0; n < 4; ++n) {
            int row = n*16 + l15;
            int off = (row << 8) | (((kd*4 + l4) ^ (row & 7)) << 4);
            kf[n] = *(const bf16x8*)((const char*)Ksb + off);
          }
          #pragma unroll
          for (int m = 0; m < 2; ++m)
            #pragma unroll
            for (int n = 0; n < 4; ++n)
              sacc[m][n] = __builtin_amdgcn_mfma_f32_16x16x32_bf16(qf[m][kd], kf[n], sacc[m][n], 0, 0, 0);
        }
        __builtin_amdgcn_s_setprio(0);

        if (st >= 2*qb) {
          #pragma unroll
          for (int n = 0; n < 4; ++n) {
            int ki = kv0 + n*16 + l15;
            #pragma unroll
            for (int m = 0; m < 2; ++m)
              #pragma unroll
              for (int r = 0; r < 4; ++r) {
                int qi = q0w + m*16 + l4*4 + r;
                if (ki > qi) sacc[m][n][r] = -1e30f;
              }
          }
        }

        float pr[2][4][4];
        #pragma unroll
        for (int m = 0; m < 2; ++m) {
          #pragma unroll
          for (int r = 0; r < 4; ++r) {
            float s0 = sacc[m][0][r], s1 = sacc[m][1][r];
            float s2 = sacc[m][2][r], s3 = sacc[m][3][r];
            float vm = fmaxf(fmaxf(s0, s1), fmaxf(s2, s3));
            vm = red16_max(vm);
            float mo = mrun[m][r];
            float mnew = fmaxf(mo, vm);
            float al = __expf(mo - mnew);
            float p0 = __expf(s0 - mnew), p1 = __expf(s1 - mnew);
            float p2 = __expf(s2 - mnew), p3 = __expf(s3 - mnew);
            float rs = red16_sum((p0 + p1) + (p2 + p3));
            mrun[m][r] = mnew;
            lrun[m][r] = lrun[m][r]*al + rs;
            #pragma unroll
            for (int dn = 0; dn < 8; ++dn) oacc[m][dn][r] *= al;
            pr[m][r][0] = p0; pr[m][r][1] = p1; pr[m][r][2] = p2; pr[m][r][3] = p3;
          }
        }

        #pragma unroll
        for (int kvh = 0; kvh < 2; ++kvh) {
          #pragma unroll
          for (int m = 0; m < 2; ++m)
            #pragma unroll
            for (int nn = 0; nn < 2; ++nn) {
              int n = kvh*2 + nn;
              bf16x4 w4;
              w4[0] = (__bf16)pr[m][0][n]; w4[1] = (__bf16)pr[m][1][n];
              w4[2] = (__bf16)pr[m][2][n]; w4[3] = (__bf16)pr[m][3][n];
              *(bf16x4*)((char*)Pw + ((nn*4 + (l15 >> 2))*2 + m)*128
                                   + (l15 & 3)*32 + l4*8) = w4;
            }
          const char* pb = (const char*)Pw + l4*512 + l15*8;
          bf16x4 a00 = tr16(pb);
          bf16x4 a01 = tr16(pb + 256);
          bf16x4 a10 = tr16(pb + 128);
          bf16x4 a11 = tr16(pb + 384);
          const char* vb = (const char*)Vsb + l4*2048 + l15*8 + kvh*8192;
          bf16x4 b0[8], b1[8];
          #pragma unroll
          for (int dn = 0; dn < 8; ++dn) {
            b0[dn] = tr16(vb + dn*128);
            b1[dn] = tr16(vb + dn*128 + 1024);
          }
          WAIT_LGKM0; SGB0;
          bf16x8 pa0 = __builtin_shufflevector(a00, a01, 0,1,2,3,4,5,6,7);
          bf16x8 pa1 = __builtin_shufflevector(a10, a11, 0,1,2,3,4,5,6,7);
          __builtin_amdgcn_s_setprio(1);
          #pragma unroll
          for (int dn = 0; dn < 8; ++dn) {
            bf16x8 v8 = __builtin_shufflevector(b0[dn], b1[dn], 0,1,2,3,4,5,6,7);
            oacc[0][dn] = __builtin_amdgcn_mfma_f32_16x16x32_bf16(pa0, v8, oacc[0][dn], 0, 0, 0);
            oacc[1][dn] = __builtin_amdgcn_mfma_f32_16x16x32_bf16(pa1, v8, oacc[1][dn], 0, 0, 0);
          }
          __builtin_amdgcn_s_setprio(0);
        }
      }

      WAIT_VM0;
      __builtin_amdgcn_s_barrier();
      SGB0;
    }

    const size_t obase = ((size_t)(b*SS + q0w)) * DIM + h*HD;
    #pragma unroll
    for (int m = 0; m < 2; ++m) {
      #pragma unroll
      for (int r = 0; r < 4; ++r) {
        float inv = 1.0f / lrun[m][r];
        int srow = m*16 + l4*4 + r;
        #pragma unroll
        for (int dn = 0; dn < 8; ++dn)
          O[obase + (size_t)srow*DIM + dn*16 + l15] = f2bf(oacc[m][dn][r] * inv);
      }
    }
  }
}

extern "C" void kernel_launch(void* const* d_in, const int* in_sizes, int n_in,
                              void* d_out, int out_size, void* d_ws, size_t ws_size,
                              hipStream_t stream) {
  const float* x   = (const float*)d_in[0];
  const float* Wq  = (const float*)d_in[1];
  const float* Wkv = (const float*)d_in[2];
  const float* Wo  = (const float*)d_in[3];

  if (ws_size < (160ull << 20)) return;
  char* ws = (char*)d_ws;
  u16* xb   = (u16*)(ws);                  // 32 MB [4096][4096]
  u16* Wqb  = (u16*)(ws + (32ull  << 20)); // 32 MB [4096][4096]  \ fused W rows 0..6143
  u16* Wkvb = (u16*)(ws + (64ull  << 20)); // 16 MB [2048][4096]  /
  u16* Wob  = (u16*)(ws + (80ull  << 20)); // 32 MB [4096][4096]
  u16* QKVb = (u16*)(ws + (112ull << 20)); // 48 MB [4096][6144]
  u16* attnb = xb;                         // alias after projections

  // fp32 -> bf16, one launch (x | Wq | Wkv | Wo)
  f2b4_kernel<<<28672, 256, 0, stream>>>(x, Wq, Wkv, Wo, xb, Wqb, Wkvb, Wob);

  // fused QKV projection: [4096][6144] = xb @ [Wq;Wkv]^T ; QSCALE on Q cols only
  gemm256<0><<<dim3(16*24), 512, 0, stream>>>(xb, Wqb, QKVb,
                                              MROWS, QKVP, DIM, 24, DIM, QSCALE, 1.0f);

  attn_kernel<<<dim3(8, NHEADS, BB), 256, 0, stream>>>(QKVb, attnb);

  // output projection (fp32 out)
  gemm256<1><<<dim3(16*16), 512, 0, stream>>>(attnb, Wob, d_out,
                                              MROWS, DIM, DIM, 16, 0, 1.0f, 1.0f);
}

// Round 10
// 525.974 us; speedup vs baseline: 6.2609x; 1.0334x over previous
//
#include <hip/hip_runtime.h>

typedef __bf16 bf16x8 __attribute__((ext_vector_type(8)));
typedef __bf16 bf16x4 __attribute__((ext_vector_type(4)));
typedef float f32x4 __attribute__((ext_vector_type(4)));
typedef unsigned short u16;
typedef unsigned short u16x8 __attribute__((ext_vector_type(8)));

#define DIM 4096
#define NHEADS 32
#define NKV 8
#define HD 128
#define BB 2
#define SS 2048
#define MROWS (BB*SS)        // 4096
#define QKVP 6144            // fused QKV row pitch (4096 Q | 1024 K | 1024 V)
#define QSCALE 0.08838834764831843f  // 1/sqrt(128)

#define WAIT_LGKM0 asm volatile("s_waitcnt lgkmcnt(0)" ::: "memory")
#define WAIT_VM0   asm volatile("s_waitcnt vmcnt(0)" ::: "memory")
#define WAIT_VM4   asm volatile("s_waitcnt vmcnt(4)" ::: "memory")
#define SGB0       __builtin_amdgcn_sched_barrier(0)

__device__ __forceinline__ u16 f2bf(float f) {
  unsigned int u = __float_as_uint(f);
  u += 0x7fffu + ((u >> 16) & 1u);   // round-to-nearest-even
  return (u16)(u >> 16);
}

__device__ __forceinline__ void gload16(const void* g, void* l) {
  __builtin_amdgcn_global_load_lds(
      (const __attribute__((address_space(1))) unsigned int*)g,
      (__attribute__((address_space(3))) unsigned int*)l, 16, 0, 0);
}

__device__ __forceinline__ bf16x4 tr16(const void* p) {
  bf16x4 d;
  asm volatile("ds_read_b64_tr_b16 %0, %1"
               : "=v"(d)
               : "v"((const __attribute__((address_space(3))) u16*)p)
               : "memory");
  return d;
}

template<int CTRL>
__device__ __forceinline__ float dpp_ror(float x) {
  return __int_as_float(__builtin_amdgcn_update_dpp(
      0, __float_as_int(x), CTRL, 0xF, 0xF, false));
}
__device__ __forceinline__ float red16_max(float v) {
  v = fmaxf(v, dpp_ror<0x121>(v));
  v = fmaxf(v, dpp_ror<0x122>(v));
  v = fmaxf(v, dpp_ror<0x124>(v));
  v = fmaxf(v, dpp_ror<0x128>(v));
  return v;
}
__device__ __forceinline__ float red16_sum(float v) {
  v += dpp_ror<0x121>(v);
  v += dpp_ror<0x122>(v);
  v += dpp_ror<0x124>(v);
  v += dpp_ror<0x128>(v);
  return v;
}

// ---------------- fp32 -> bf16 conversion, all 4 tensors in one launch ----------------
__global__ __launch_bounds__(256) void f2b4_kernel(
    const float* __restrict__ xa, const float* __restrict__ xb,
    const float* __restrict__ xc, const float* __restrict__ xd,
    u16* __restrict__ oa, u16* __restrict__ ob,
    u16* __restrict__ oc, u16* __restrict__ od) {
  int i = blockIdx.x * 256 + threadIdx.x;
  const float* in; u16* out; int k;
  if (i < 2097152)      { in = xa; out = oa; k = i; }
  else if (i < 4194304) { in = xb; out = ob; k = i - 2097152; }
  else if (i < 5242880) { in = xc; out = oc; k = i - 4194304; }
  else                  { in = xd; out = od; k = i - 5242880; }
  const float4* in4 = (const float4*)in;
  float4 a = in4[2*(size_t)k];
  float4 b = in4[2*(size_t)k + 1];
  u16x8 o;
  o[0]=f2bf(a.x); o[1]=f2bf(a.y); o[2]=f2bf(a.z); o[3]=f2bf(a.w);
  o[4]=f2bf(b.x); o[5]=f2bf(b.y); o[6]=f2bf(b.z); o[7]=f2bf(b.w);
  ((u16x8*)out)[k] = o;
}

// ---------------- 256x256 / BK=64 / 8-wave GEMM, m201 8-phase template ----------------
// dbuf per K-tile (d = tile&1), 2 halves (128 rows) per matrix-tile.
// Iter j covers tiles ta=2j (dbuf0), tb=2j+1 (dbuf1); 8 phases, each:
// {ds_read frag subtile ; stage ONE half-tile ; barrier ; lgkm0 ; 16 MFMA ; bar}.
// Stage map: P1:Ah0(tb) P2:Ah1(tb) P3:Bh0(tc) P4:Bh1(tc) P5:Ah0(tc) P6:Ah1(tc)
// P7:Bh0(td) P8:Bh1(td)  (tc=2j+2, td=2j+3). Quadrants (qm,qn) per phase:
// (0,0)(0,1)(1,1)(1,0) x2 — every half-tile's last LDS read strictly precedes
// its overwrite (audited). vmcnt(4) at P4/P8 pins exactly the tile needed in
// the next 4 phases; never drains mid-loop. LDS row r (128B): stored 16B-chunk
// c holds source chunk c^(r&7) (both-sides swizzle, rule 21; 2-way = free).
template<int OUTF32>
__global__ __launch_bounds__(512, 2) void gemm256(
    const u16* __restrict__ A, const u16* __restrict__ Bm, void* __restrict__ C,
    int M, int N, int K, int nbx, int acut, float a0, float a1) {
  __shared__ char smem[131072];   // A: 2dbuf x 2half x 16KB @0 ; B same @65536

  const int t = threadIdx.x;
  const int l = t & 63, w = t >> 6;
  const int l15 = l & 15, l4 = l >> 4;
  const int wm = w >> 2, wn = w & 3;      // 2 x 4 wave grid, 128x64 per wave

  // bijective XCD swizzle (nwg % 8 == 0 for all our grids)
  const int nwg = gridDim.x;
  const int cpx = nwg >> 3;
  const int sw = (blockIdx.x & 7) * cpx + (blockIdx.x >> 3);
  const int bx = sw % nbx, by = sw / nbx;
  const int row0 = by * 256, col0 = bx * 256;
  const float alpha = (col0 < acut) ? a0 : a1;

  f32x4 acc[8][4] = {};

  // ---- stage addressing: half-tile = 1024 16B-units; thread t covers units
  // u=t (row j1=t>>3, 0..63) and u+512 (row j1+64). chunk swizzle cs = c^(j&7)
  const int j1 = t >> 3;
  const int cs1 = (t & 7) ^ (j1 & 7);
  const u16* pA = A  + (size_t)(row0 + j1) * K + cs1 * 8;
  const u16* pB = Bm + (size_t)(col0 + j1) * K + cs1 * 8;
  const int nt = K >> 6;                  // K-tiles of 64
  const int ldst = w * 1024;              // wave-uniform LDS dest

  auto stA = [&](int tile, int h) {
    if (tile >= nt) return;
    const u16* s = pA + (size_t)(h * 128) * K + tile * 64;
    char* dst = (char*)smem + (tile & 1) * 32768 + h * 16384 + ldst;
    gload16(s, dst);
    gload16(s + (size_t)64 * K, dst + 8192);
  };
  auto stB = [&](int tile, int h) {
    if (tile >= nt) return;
    const u16* s = pB + (size_t)(h * 128) * K + tile * 64;
    char* dst = (char*)smem + 65536 + (tile & 1) * 32768 + h * 16384 + ldst;
    gload16(s, dst);
    gload16(s + (size_t)64 * K, dst + 8192);
  };

  // ---- fragment read offsets: chunk = (kk*4+l4)^(l15&7), row byte l15*128 ----
  const int cxk0 = ((0 * 4 + l4) ^ (l15 & 7)) * 16;
  const int cxk1 = ((1 * 4 + l4) ^ (l15 & 7)) * 16;
  const int abase = wm * 16384 + l15 * 128;                    // + d*32768 + qm*8192 + i*2048
  const int bbase = 65536 + (wn >> 1) * 16384 + (wn & 1) * 8192 + l15 * 128;  // + d*32768 + qn*4096 + n*2048

  bf16x8 Ar[4][2], B0r[2][2], B1r[2][2];

  auto rdA = [&](int d, int qm) {
    const char* p = (const char*)smem + d * 32768 + qm * 8192 + abase;
    #pragma unroll
    for (int i = 0; i < 4; ++i) {
      Ar[i][0] = *(const bf16x8*)(p + i * 2048 + cxk0);
      Ar[i][1] = *(const bf16x8*)(p + i * 2048 + cxk1);
    }
  };
  auto rdB = [&](bf16x8 (&BR)[2][2], int d, int qn) {
    const char* p = (const char*)smem + d * 32768 + qn * 4096 + bbase;
    #pragma unroll
    for (int n = 0; n < 2; ++n) {
      BR[n][0] = *(const bf16x8*)(p + n * 2048 + cxk0);
      BR[n][1] = *(const bf16x8*)(p + n * 2048 + cxk1);
    }
  };

#define MM16(QM, QN, BR) \
  do { \
    __builtin_amdgcn_s_setprio(1); \
    _Pragma("unroll") \
    for (int i = 0; i < 4; ++i) \
      _Pragma("unroll") \
      for (int n = 0; n < 2; ++n) \
        _Pragma("unroll") \
        for (int kk = 0; kk < 2; ++kk) \
          acc[(QM)*4 + i][(QN)*2 + n] = __builtin_amdgcn_mfma_f32_16x16x32_bf16( \
              Ar[i][kk], BR[n][kk], acc[(QM)*4 + i][(QN)*2 + n], 0, 0, 0); \
    __builtin_amdgcn_s_setprio(0); \
  } while (0)

#define PH_BAR  __builtin_amdgcn_s_barrier()

  // prologue: Bh0(0),Bh1(0),Ah0(0),Ah1(0),Bh0(1),Bh1(1); t0 landed via vmcnt(4)
  stB(0, 0); stB(0, 1); stA(0, 0); stA(0, 1); stB(1, 0); stB(1, 1);
  WAIT_VM4;
  PH_BAR;

  const int niter = nt >> 1;
  for (int j = 0; j < niter; ++j) {
    const int tb = 2 * j + 1, tc = 2 * j + 2, td = 2 * j + 3;

    // P1: (qm0,qn0) t_a(dbuf0) | rd A qm0 + B0 | stage Ah0(tb)
    rdA(0, 0); rdB(B0r, 0, 0); SGB0;
    stA(tb, 0);
    PH_BAR; WAIT_LGKM0; SGB0;
    MM16(0, 0, B0r);
    PH_BAR;

    // P2: (qm0,qn1) | rd B1 | stage Ah1(tb)
    rdB(B1r, 0, 1); SGB0;
    stA(tb, 1);
    PH_BAR; WAIT_LGKM0; SGB0;
    MM16(0, 1, B1r);
    PH_BAR;

    // P3: (qm1,qn1) | rd A qm1 | stage Bh0(tc)
    rdA(0, 1); SGB0;
    stB(tc, 0);
    PH_BAR; WAIT_LGKM0; SGB0;
    MM16(1, 1, B1r);
    PH_BAR;

    // P4: (qm1,qn0) | no reads | stage Bh1(tc) | vmcnt(4): tb fully landed
    stB(tc, 1);
    PH_BAR;
    MM16(1, 0, B0r);
    if (tc < nt) { WAIT_VM4; } else { WAIT_VM0; }
    PH_BAR;

    // P5: (qm0,qn0) t_b(dbuf1) | rd A qm0 + B0 | stage Ah0(tc)
    rdA(1, 0); rdB(B0r, 1, 0); SGB0;
    stA(tc, 0);
    PH_BAR; WAIT_LGKM0; SGB0;
    MM16(0, 0, B0r);
    PH_BAR;

    // P6: (qm0,qn1) | rd B1 | stage Ah1(tc)
    rdB(B1r, 1, 1); SGB0;
    stA(tc, 1);
    PH_BAR; WAIT_LGKM0; SGB0;
    MM16(0, 1, B1r);
    PH_BAR;

    // P7: (qm1,qn1) | rd A qm1 | stage Bh0(td)
    rdA(1, 1); SGB0;
    stB(td, 0);
    PH_BAR; WAIT_LGKM0; SGB0;
    MM16(1, 1, B1r);
    PH_BAR;

    // P8: (qm1,qn0) | no reads | stage Bh1(td) | vmcnt(4): tc fully landed
    stB(td, 1);
    PH_BAR;
    MM16(1, 0, B0r);
    if (td < nt) { WAIT_VM4; } else { WAIT_VM0; }
    PH_BAR;
  }

  // epilogue: C/D layout col=lane&15, row=(lane>>4)*4+reg
  #pragma unroll
  for (int mi = 0; mi < 8; ++mi) {
    #pragma unroll
    for (int ni = 0; ni < 4; ++ni) {
      #pragma unroll
      for (int r = 0; r < 4; ++r) {
        size_t rr = (size_t)(row0 + wm*128 + mi*16 + l4*4 + r);
        size_t cc = (size_t)(col0 + wn*64 + ni*16 + l15);
        float v = acc[mi][ni][r] * alpha;
        if (OUTF32) ((float*)C)[rr*(size_t)N + cc] = v;
        else        ((u16*)C)[rr*(size_t)N + cc] = f2bf(v);
      }
    }
  }
#undef MM16
#undef PH_BAR
}

// ---------------- causal GQA flash attention (QKVP pitch) ----------------
__global__ __launch_bounds__(256, 2) void attn_kernel(
    const u16* __restrict__ QKV,  // [4096][6144]: 0..4095 Q | 4096..5119 K | 5120..6143 V
    u16* __restrict__ O) {        // [4096][4096]
  __shared__ u16 Ks[2][64*128];
  __shared__ u16 Vs[2][64*128];
  __shared__ u16 Ps[4][1024];
  const int t = threadIdx.x;
  const int l = t & 63, w = t >> 6;
  const int l15 = l & 15, l4 = l >> 4;
  const int pair = blockIdx.x, h = blockIdx.y, b = blockIdx.z;
  const int hkv = h >> 2;
  const u16* Kg = QKV + (size_t)(b*SS) * QKVP + DIM + hkv*HD;
  const u16* Vg = Kg + NKV*HD;
  u16* Pw = &Ps[w][0];

  auto stage = [&](u16* Ksb, u16* Vsb, int kv0) {
    const u16* Kr = Kg + (size_t)kv0 * QKVP;
    const u16* Vr = Vg + (size_t)kv0 * QKVP;
    #pragma unroll
    for (int i = 0; i < 4; ++i) {
      int o = i*4096 + w*1024 + l*16;
      int row = o >> 8;
      int sc = l15 ^ (row & 7);
      gload16((const char*)(Kr + (size_t)row * QKVP) + sc*16,
              (char*)Ksb + i*4096 + w*1024);
    }
    #pragma unroll
    for (int i = 0; i < 4; ++i) {
      int cb = i*4 + w;
      int kv = cb*4 + ((l & 7) >> 1);
      int d0 = ((l >> 3) << 4) + (l & 1)*8;
      gload16((const char*)(Vr + (size_t)kv * QKVP + d0),
              (char*)Vsb + cb*1024);
    }
  };

  for (int half = 0; half < 2; ++half) {
    const int qb = half ? (15 - pair) : pair;
    const int q0 = qb * 128;
    const int q0w = q0 + w*32;

    const size_t qbase = ((size_t)(b*SS + q0w)) * QKVP + h*HD;
    bf16x8 qf[2][4];
    #pragma unroll
    for (int m = 0; m < 2; ++m)
      #pragma unroll
      for (int kd = 0; kd < 4; ++kd)
        qf[m][kd] = *(const bf16x8*)&QKV[qbase + (size_t)(m*16 + l15)*QKVP + kd*32 + l4*8];

    f32x4 oacc[2][8] = {};
    float mrun[2][4], lrun[2][4];
    #pragma unroll
    for (int m = 0; m < 2; ++m)
      #pragma unroll
      for (int r = 0; r < 4; ++r) { mrun[m][r] = -1e30f; lrun[m][r] = 0.f; }

    const int nst = 2*qb + 2;
    stage(Ks[0], Vs[0], 0);
    WAIT_VM0;
    __builtin_amdgcn_s_barrier();
    SGB0;

    for (int st = 0; st < nst; ++st) {
      const int kv0 = st * 64;
      u16* Ksb = Ks[st & 1];
      u16* Vsb = Vs[st & 1];
      if (st + 1 < nst) stage(Ks[(st+1) & 1], Vs[(st+1) & 1], kv0 + 64);

      if (kv0 <= q0w + 31) {
        f32x4 sacc[2][4] = {};
        __builtin_amdgcn_s_setprio(1);
        #pragma unroll
        for (int kd = 0; kd < 4; ++kd) {
          bf16x8 kf[4];
          #pragma unroll
          for (int n = 0; n < 4; ++n) {
            int row = n*16 + l15;
            int off = (row << 8) | (((kd*4 + l4) ^ (row & 7)) << 4);
            kf[n] = *(const bf16x8*)((const char*)Ksb + off);
          }
          #pragma unroll
          for (int m = 0; m < 2; ++m)
            #pragma unroll
            for (int n = 0; n < 4; ++n)
              sacc[m][n] = __builtin_amdgcn_mfma_f32_16x16x32_bf16(qf[m][kd], kf[n], sacc[m][n], 0, 0, 0);
        }
        __builtin_amdgcn_s_setprio(0);

        if (st >= 2*qb) {
          #pragma unroll
          for (int n = 0; n < 4; ++n) {
            int ki = kv0 + n*16 + l15;
            #pragma unroll
            for (int m = 0; m < 2; ++m)
              #pragma unroll
              for (int r = 0; r < 4; ++r) {
                int qi = q0w + m*16 + l4*4 + r;
                if (ki > qi) sacc[m][n][r] = -1e30f;
              }
          }
        }

        float pr[2][4][4];
        #pragma unroll
        for (int m = 0; m < 2; ++m) {
          #pragma unroll
          for (int r = 0; r < 4; ++r) {
            float s0 = sacc[m][0][r], s1 = sacc[m][1][r];
            float s2 = sacc[m][2][r], s3 = sacc[m][3][r];
            float vm = fmaxf(fmaxf(s0, s1), fmaxf(s2, s3));
            vm = red16_max(vm);
            float mo = mrun[m][r];
            float mnew = fmaxf(mo, vm);
            float al = __expf(mo - mnew);
            float p0 = __expf(s0 - mnew), p1 = __expf(s1 - mnew);
            float p2 = __expf(s2 - mnew), p3 = __expf(s3 - mnew);
            float rs = red16_sum((p0 + p1) + (p2 + p3));
            mrun[m][r] = mnew;
            lrun[m][r] = lrun[m][r]*al + rs;
            #pragma unroll
            for (int dn = 0; dn < 8; ++dn) oacc[m][dn][r] *= al;
            pr[m][r][0] = p0; pr[m][r][1] = p1; pr[m][r][2] = p2; pr[m][r][3] = p3;
          }
        }

        #pragma unroll
        for (int kvh = 0; kvh < 2; ++kvh) {
          #pragma unroll
          for (int m = 0; m < 2; ++m)
            #pragma unroll
            for (int nn = 0; nn < 2; ++nn) {
              int n = kvh*2 + nn;
              bf16x4 w4;
              w4[0] = (__bf16)pr[m][0][n]; w4[1] = (__bf16)pr[m][1][n];
              w4[2] = (__bf16)pr[m][2][n]; w4[3] = (__bf16)pr[m][3][n];
              *(bf16x4*)((char*)Pw + ((nn*4 + (l15 >> 2))*2 + m)*128
                                   + (l15 & 3)*32 + l4*8) = w4;
            }
          const char* pb = (const char*)Pw + l4*512 + l15*8;
          bf16x4 a00 = tr16(pb);
          bf16x4 a01 = tr16(pb + 256);
          bf16x4 a10 = tr16(pb + 128);
          bf16x4 a11 = tr16(pb + 384);
          const char* vb = (const char*)Vsb + l4*2048 + l15*8 + kvh*8192;
          bf16x4 b0[8], b1[8];
          #pragma unroll
          for (int dn = 0; dn < 8; ++dn) {
            b0[dn] = tr16(vb + dn*128);
            b1[dn] = tr16(vb + dn*128 + 1024);
          }
          WAIT_LGKM0; SGB0;
          bf16x8 pa0 = __builtin_shufflevector(a00, a01, 0,1,2,3,4,5,6,7);
          bf16x8 pa1 = __builtin_shufflevector(a10, a11, 0,1,2,3,4,5,6,7);
          __builtin_amdgcn_s_setprio(1);
          #pragma unroll
          for (int dn = 0; dn < 8; ++dn) {
            bf16x8 v8 = __builtin_shufflevector(b0[dn], b1[dn], 0,1,2,3,4,5,6,7);
            oacc[0][dn] = __builtin_amdgcn_mfma_f32_16x16x32_bf16(pa0, v8, oacc[0][dn], 0, 0, 0);
            oacc[1][dn] = __builtin_amdgcn_mfma_f32_16x16x32_bf16(pa1, v8, oacc[1][dn], 0, 0, 0);
          }
          __builtin_amdgcn_s_setprio(0);
        }
      }

      WAIT_VM0;
      __builtin_amdgcn_s_barrier();
      SGB0;
    }

    const size_t obase = ((size_t)(b*SS + q0w)) * DIM + h*HD;
    #pragma unroll
    for (int m = 0; m < 2; ++m) {
      #pragma unroll
      for (int r = 0; r < 4; ++r) {
        float inv = 1.0f / lrun[m][r];
        int srow = m*16 + l4*4 + r;
        #pragma unroll
        for (int dn = 0; dn < 8; ++dn)
          O[obase + (size_t)srow*DIM + dn*16 + l15] = f2bf(oacc[m][dn][r] * inv);
      }
    }
  }
}

extern "C" void kernel_launch(void* const* d_in, const int* in_sizes, int n_in,
                              void* d_out, int out_size, void* d_ws, size_t ws_size,
                              hipStream_t stream) {
  const float* x   = (const float*)d_in[0];
  const float* Wq  = (const float*)d_in[1];
  const float* Wkv = (const float*)d_in[2];
  const float* Wo  = (const float*)d_in[3];

  if (ws_size < (160ull << 20)) return;
  char* ws = (char*)d_ws;
  u16* xb   = (u16*)(ws);                  // 32 MB [4096][4096]
  u16* Wqb  = (u16*)(ws + (32ull  << 20)); // 32 MB [4096][4096]  \ fused W rows 0..6143
  u16* Wkvb = (u16*)(ws + (64ull  << 20)); // 16 MB [2048][4096]  /
  u16* Wob  = (u16*)(ws + (80ull  << 20)); // 32 MB [4096][4096]
  u16* QKVb = (u16*)(ws + (112ull << 20)); // 48 MB [4096][6144]
  u16* attnb = xb;                         // alias after projections

  // fp32 -> bf16, one launch (x | Wq | Wkv | Wo)
  f2b4_kernel<<<28672, 256, 0, stream>>>(x, Wq, Wkv, Wo, xb, Wqb, Wkvb, Wob);

  // fused QKV projection: [4096][6144] = xb @ [Wq;Wkv]^T ; QSCALE on Q cols only
  gemm256<0><<<dim3(16*24), 512, 0, stream>>>(xb, Wqb, QKVb,
                                              MROWS, QKVP, DIM, 24, DIM, QSCALE, 1.0f);

  attn_kernel<<<dim3(8, NHEADS, BB), 256, 0, stream>>>(QKVb, attnb);

  // output projection (fp32 out)
  gemm256<1><<<dim3(16*16), 512, 0, stream>>>(attnb, Wob, d_out,
                                              MROWS, DIM, DIM, 16, 0, 1.0f, 1.0f);
}